// Round 3
// baseline (753.558 us; speedup 1.0000x reference)
//
#include <hip/hip_runtime.h>
#include <math.h>

#define N 8192
#define D 64
#define KSPLIT 8

typedef _Float16 half_t;
typedef _Float16 f16x8 __attribute__((ext_vector_type(8)));
typedef _Float16 f16x4 __attribute__((ext_vector_type(4)));
typedef float f32x4 __attribute__((ext_vector_type(4)));

#define MFMA32(a, b, c) __builtin_amdgcn_mfma_f32_16x16x32_f16((a), (b), (c), 0, 0, 0)
#define MFMA16(a, b, c) __builtin_amdgcn_mfma_f32_16x16x16f16((a), (b), (c), 0, 0, 0)

// split a f32 into f16 hi + f16 lo (v ~= hi + lo, rel err ~2^-22)
#define SPLIT(v, H, L) { half_t _h = (half_t)(v); (H) = _h; (L) = (half_t)((v) - (float)_h); }

// ---------------------------------------------------------------------------
// K1: Q = (X@Wq)*0.125 (f32), K = X@Wk as f16 hi/lo. 16 rows/block.
// ---------------------------------------------------------------------------
__global__ __launch_bounds__(256) void proj_kernel(
    const float* __restrict__ Wq, const float* __restrict__ Wk,
    const float* __restrict__ X, const float* __restrict__ Y,
    float* __restrict__ Qx, float* __restrict__ Qy,
    half_t* __restrict__ Khix, half_t* __restrict__ Klox,
    half_t* __restrict__ Khiy, half_t* __restrict__ Kloy)
{
    __shared__ float sWq[64][64];
    __shared__ float sWk[64][64];
    __shared__ float sIn[16][64];
    const int t = threadIdx.x;
#pragma unroll
    for (int p = 0; p < 16; ++p) {
        int idx = p * 256 + t;
        sWq[idx >> 6][idx & 63] = Wq[idx];
        sWk[idx >> 6][idx & 63] = Wk[idx];
    }
    const int R0 = blockIdx.x * 16;
    const float* src; float* dq; half_t* dkh; half_t* dkl; int r0;
    if (R0 < N) { src = X; dq = Qx; dkh = Khix; dkl = Klox; r0 = R0; }
    else        { src = Y; dq = Qy; dkh = Khiy; dkl = Kloy; r0 = R0 - N; }
#pragma unroll
    for (int p = 0; p < 4; ++p) {
        int idx = p * 256 + t;
        sIn[idx >> 6][idx & 63] = src[(size_t)r0 * D + idx];
    }
    __syncthreads();
    const int c = t & 63;
    const int rb = t >> 6;
#pragma unroll
    for (int rr = 0; rr < 4; ++rr) {
        int r = rr * 4 + rb;
        float aq = 0.f, ak = 0.f;
#pragma unroll
        for (int k = 0; k < 64; ++k) {
            float xv = sIn[r][k];
            aq = fmaf(xv, sWq[k][c], aq);
            ak = fmaf(xv, sWk[k][c], ak);
        }
        dq[(size_t)(r0 + r) * D + c] = aq * 0.125f;  // 1/sqrt(64) folded into Q
        half_t hh = (half_t)ak;
        dkh[(size_t)(r0 + r) * D + c] = hh;
        dkl[(size_t)(r0 + r) * D + c] = (half_t)(ak - (float)hh);
    }
}

// ---------------------------------------------------------------------------
// K2: zt prep: zt[d][row] = f16 hi/lo of input[row][d] (transposed, split).
// ---------------------------------------------------------------------------
__global__ __launch_bounds__(256) void ztprep_kernel(
    const float* __restrict__ X, const float* __restrict__ Y,
    half_t* __restrict__ zthix, half_t* __restrict__ ztlox,
    half_t* __restrict__ zthiy, half_t* __restrict__ ztloy)
{
    __shared__ float T[64][68];   // [d][r]
    const int t = threadIdx.x;
    const float* src = blockIdx.y ? Y : X;
    half_t* dh = blockIdx.y ? zthiy : zthix;
    half_t* dl = blockIdx.y ? ztloy : ztlox;
    const int r0 = blockIdx.x * 64;
#pragma unroll
    for (int p = 0; p < 4; ++p) {
        int r = p * 16 + (t >> 4);
        int c4 = (t & 15) * 4;
        f32x4 v = *(const f32x4*)&src[(size_t)(r0 + r) * D + c4];
        T[c4 + 0][r] = v[0]; T[c4 + 1][r] = v[1];
        T[c4 + 2][r] = v[2]; T[c4 + 3][r] = v[3];
    }
    __syncthreads();
    const int d = t >> 2, cb = (t & 3) * 16;
    f16x8 h0, h1, l0, l1;
#pragma unroll
    for (int i = 0; i < 8; ++i) { float v = T[d][cb + i];     SPLIT(v, h0[i], l0[i]); }
#pragma unroll
    for (int i = 0; i < 8; ++i) { float v = T[d][cb + 8 + i]; SPLIT(v, h1[i], l1[i]); }
    *(f16x8*)&dh[(size_t)d * N + r0 + cb]     = h0;
    *(f16x8*)&dh[(size_t)d * N + r0 + cb + 8] = h1;
    *(f16x8*)&dl[(size_t)d * N + r0 + cb]     = l0;
    *(f16x8*)&dl[(size_t)d * N + r0 + cb + 8] = l1;
}

// ---------------------------------------------------------------------------
// K3: flash attention, MFMA f16 3-product. ZERO LDS / ZERO syncthreads.
// S^T = K·Q^T via 16x16x32; P stays in registers: S's C-layout (kv=4*quad+r,
// q=lane&15) IS the B-operand layout of 16x16x16 MFMA (k=4*quad+j, n=lane&15),
// so PV = ZT·P uses v_mfma_f32_16x16x16_f16 with ZT A-frags from global.
// grid (64, 2, KSPLIT); 4 waves x 32 q per block.
// ---------------------------------------------------------------------------
__global__ __launch_bounds__(256, 3) void attn_kernel(
    const float* __restrict__ Qx, const float* __restrict__ Qy,
    const half_t* __restrict__ Khix, const half_t* __restrict__ Klox,
    const half_t* __restrict__ Khiy, const half_t* __restrict__ Kloy,
    const half_t* __restrict__ zthix, const half_t* __restrict__ ztlox,
    const half_t* __restrict__ zthiy, const half_t* __restrict__ ztloy,
    float* __restrict__ Opart, float* __restrict__ mpart, float* __restrict__ lpart)
{
    const int side = blockIdx.y;
    const float*  Q   = side ? Qy    : Qx;
    const half_t* Khi = side ? Khiy  : Khix;
    const half_t* Klo = side ? Kloy  : Klox;
    const half_t* Zhi = side ? zthiy : zthix;
    const half_t* Zlo = side ? ztloy : ztlox;
    const int t = threadIdx.x, w = t >> 6, lane = t & 63;
    const int c16 = lane & 15, quad = lane >> 4;
    const int q0 = blockIdx.x * 128 + w * 32;
    const int sp = blockIdx.z;
    const int kvbase = sp * (N / KSPLIT);

    // Q fragments (B-operand of 16x16x32: n=lane&15=q, k=quad*8+j)
    f16x8 qh[2][2], ql[2][2];   // [qg][ks]
#pragma unroll
    for (int qg = 0; qg < 2; ++qg)
#pragma unroll
        for (int ks = 0; ks < 2; ++ks) {
            const float* s = &Q[(size_t)(q0 + 16 * qg + c16) * D + ks * 32 + quad * 8];
            f32x4 v0 = *(const f32x4*)s;
            f32x4 v1 = *(const f32x4*)(s + 4);
            f16x8 h, l;
#pragma unroll
            for (int i = 0; i < 4; ++i) { SPLIT(v0[i], h[i],     l[i]); }
#pragma unroll
            for (int i = 0; i < 4; ++i) { SPLIT(v1[i], h[4 + i], l[4 + i]); }
            qh[qg][ks] = h; ql[qg][ks] = l;
        }

    f32x4 ot[4][2] = {};                      // O^T accs [dt][qg]
    float m_run[2] = {-INFINITY, -INFINITY};
    float l_run[2] = {0.f, 0.f};

    for (int tt = 0; tt < (N / KSPLIT) / 32; ++tt) {
        const int kv0 = kvbase + tt * 32;
        // ---- Z A-frags for PV (16x16x16: m=lane&15=d, k=quad*4+j) ----
        f16x4 zh[4][2], zl[4][2];   // [dt][tau]
#pragma unroll
        for (int dt = 0; dt < 4; ++dt)
#pragma unroll
            for (int tau = 0; tau < 2; ++tau) {
                size_t zo = (size_t)(16 * dt + c16) * N + kv0 + 16 * tau + quad * 4;
                zh[dt][tau] = *(const f16x4*)&Zhi[zo];
                zl[dt][tau] = *(const f16x4*)&Zlo[zo];
            }
        // ---- S^T = K·Q^T ----
        f32x4 st[2][2] = {};                  // [qg][tau]
#pragma unroll
        for (int ks = 0; ks < 2; ++ks)
#pragma unroll
            for (int tau = 0; tau < 2; ++tau) {
                size_t ko = (size_t)(kv0 + 16 * tau + c16) * D + ks * 32 + quad * 8;
                f16x8 kh = *(const f16x8*)&Khi[ko];
                f16x8 kl = *(const f16x8*)&Klo[ko];
#pragma unroll
                for (int qg = 0; qg < 2; ++qg) {
                    st[qg][tau] = MFMA32(kh, qh[qg][ks], st[qg][tau]);
                    st[qg][tau] = MFMA32(kh, ql[qg][ks], st[qg][tau]);
                    st[qg][tau] = MFMA32(kl, qh[qg][ks], st[qg][tau]);
                }
            }
        // ---- online softmax + P (register-resident, hi/lo) ----
        f16x4 ph[2][2], pl[2][2];             // [qg][tau]
#pragma unroll
        for (int qg = 0; qg < 2; ++qg) {
            float mt = fmaxf(fmaxf(fmaxf(st[qg][0][0], st[qg][0][1]),
                                   fmaxf(st[qg][0][2], st[qg][0][3])),
                             fmaxf(fmaxf(st[qg][1][0], st[qg][1][1]),
                                   fmaxf(st[qg][1][2], st[qg][1][3])));
            mt = fmaxf(mt, __shfl_xor(mt, 16));
            mt = fmaxf(mt, __shfl_xor(mt, 32));
            float mn = fmaxf(m_run[qg], mt);
            float al = __expf(m_run[qg] - mn);
            m_run[qg] = mn;
            float ss = 0.f;
#pragma unroll
            for (int tau = 0; tau < 2; ++tau)
#pragma unroll
                for (int r = 0; r < 4; ++r) {
                    float e = __expf(st[qg][tau][r] - mn);
                    st[qg][tau][r] = e; ss += e;
                }
            ss += __shfl_xor(ss, 16);
            ss += __shfl_xor(ss, 32);
            l_run[qg] = l_run[qg] * al + ss;
#pragma unroll
            for (int tau = 0; tau < 2; ++tau) {
                f16x4 h4, l4;
#pragma unroll
                for (int r = 0; r < 4; ++r) { SPLIT(st[qg][tau][r], h4[r], l4[r]); }
                ph[qg][tau] = h4; pl[qg][tau] = l4;
            }
#pragma unroll
            for (int dt = 0; dt < 4; ++dt) ot[dt][qg] *= al;
        }
        // ---- PV: O^T[d][q] += ZT[d][kv] * P[kv][q], K=16 MFMA ----
#pragma unroll
        for (int dt = 0; dt < 4; ++dt)
#pragma unroll
            for (int qg = 0; qg < 2; ++qg)
#pragma unroll
                for (int tau = 0; tau < 2; ++tau) {
                    ot[dt][qg] = MFMA16(zh[dt][tau], ph[qg][tau], ot[dt][qg]);
                    ot[dt][qg] = MFMA16(zh[dt][tau], pl[qg][tau], ot[dt][qg]);
                    ot[dt][qg] = MFMA16(zl[dt][tau], ph[qg][tau], ot[dt][qg]);
                }
    }
    // epilogue: unnormalized O (relative to m_run) + m, l partials
    const size_t obase = (size_t)(side * KSPLIT + sp) * N;
#pragma unroll
    for (int qg = 0; qg < 2; ++qg) {
        int q = q0 + 16 * qg + c16;
#pragma unroll
        for (int dt = 0; dt < 4; ++dt)
            *(f32x4*)&Opart[(obase + q) * D + 16 * dt + 4 * quad] = ot[dt][qg];
        if (quad == 0) {
            mpart[obase + q] = m_run[qg];
            lpart[obase + q] = l_run[qg];
        }
    }
}

// ---------------------------------------------------------------------------
// K4: combine split-K partials -> xa/ya (f16 hi/lo) + squared row norms.
// ---------------------------------------------------------------------------
__global__ __launch_bounds__(256) void combine_kernel(
    const float* __restrict__ Opart, const float* __restrict__ mpart,
    const float* __restrict__ lpart,
    half_t* __restrict__ xahi, half_t* __restrict__ xalo,
    half_t* __restrict__ yahi, half_t* __restrict__ yalo,
    float* __restrict__ n2x, float* __restrict__ n2y)
{
    const int side = blockIdx.y;
    const int q = blockIdx.x * 16 + (threadIdx.x >> 4);
    const int d4 = (threadIdx.x & 15) * 4;
    float m[KSPLIT], l[KSPLIT];
#pragma unroll
    for (int s = 0; s < KSPLIT; ++s) {
        size_t b = (size_t)(side * KSPLIT + s) * N + q;
        m[s] = mpart[b]; l[s] = lpart[b];
    }
    float M = -INFINITY;
#pragma unroll
    for (int s = 0; s < KSPLIT; ++s) M = fmaxf(M, m[s]);
    float L = 0.f;
    f32x4 o = {0.f, 0.f, 0.f, 0.f};
#pragma unroll
    for (int s = 0; s < KSPLIT; ++s) {
        float sc = __expf(m[s] - M);
        L += l[s] * sc;
        f32x4 p = *(const f32x4*)&Opart[((size_t)(side * KSPLIT + s) * N + q) * D + d4];
        o += p * sc;
    }
    float inv = 1.f / L;
    o *= inv;
    float sq = o[0] * o[0] + o[1] * o[1] + o[2] * o[2] + o[3] * o[3];
#pragma unroll
    for (int off = 1; off < 16; off <<= 1) sq += __shfl_xor(sq, off);
    half_t* dh = side ? yahi : xahi;
    half_t* dl = side ? yalo : xalo;
    float*  n2 = side ? n2y  : n2x;
    if ((threadIdx.x & 15) == 0) n2[q] = sq;
    f16x4 h4, l4;
#pragma unroll
    for (int i = 0; i < 4; ++i) { SPLIT(o[i], h4[i], l4[i]); }
    *(f16x4*)&dh[(size_t)q * D + d4] = h4;
    *(f16x4*)&dl[(size_t)q * D + d4] = l4;
}

// ---------------------------------------------------------------------------
// K5: RBF via MFMA, frags straight from global (L2). Block = 4 waves (2x2),
// 128x128 out tile, 64x64 per wave. out = exp(2*dot - |xa|^2 - |ya|^2).
// ---------------------------------------------------------------------------
__global__ __launch_bounds__(256, 3) void rbf_kernel(
    const half_t* __restrict__ xahi, const half_t* __restrict__ xalo,
    const half_t* __restrict__ yahi, const half_t* __restrict__ yalo,
    const float* __restrict__ n2x, const float* __restrict__ n2y,
    float* __restrict__ out)
{
    const int t = threadIdx.x, w = t >> 6, lane = t & 63;
    const int c16 = lane & 15, quad = lane >> 4;
    const int X0 = blockIdx.y * 128 + (w >> 1) * 64;
    const int Y0 = blockIdx.x * 128 + (w & 1) * 64;
    // hoist norms (independent of the MFMA chain)
    float ny[4];
    f32x4 nx4[4];
#pragma unroll
    for (int yt = 0; yt < 4; ++yt) ny[yt] = n2y[Y0 + 16 * yt + c16];
#pragma unroll
    for (int xt = 0; xt < 4; ++xt)
        nx4[xt] = *(const f32x4*)&n2x[X0 + 16 * xt + 4 * quad];

    f32x4 acc[4][4] = {};   // [xt][yt]
#pragma unroll
    for (int ks = 0; ks < 2; ++ks) {
        f16x8 bh[4], bl[4];
#pragma unroll
        for (int yt = 0; yt < 4; ++yt) {
            size_t off = (size_t)(Y0 + 16 * yt + c16) * D + ks * 32 + quad * 8;
            bh[yt] = *(const f16x8*)&yahi[off];
            bl[yt] = *(const f16x8*)&yalo[off];
        }
#pragma unroll
        for (int xt = 0; xt < 4; ++xt) {
            size_t ao = (size_t)(X0 + 16 * xt + c16) * D + ks * 32 + quad * 8;
            f16x8 ah = *(const f16x8*)&xahi[ao];
            f16x8 al = *(const f16x8*)&xalo[ao];
#pragma unroll
            for (int yt = 0; yt < 4; ++yt) {
                acc[xt][yt] = MFMA32(ah, bh[yt], acc[xt][yt]);
                acc[xt][yt] = MFMA32(ah, bl[yt], acc[xt][yt]);
                acc[xt][yt] = MFMA32(al, bh[yt], acc[xt][yt]);
            }
        }
    }
#pragma unroll
    for (int xt = 0; xt < 4; ++xt)
#pragma unroll
        for (int r = 0; r < 4; ++r) {
            int xr = X0 + 16 * xt + 4 * quad + r;
            float nx = nx4[xt][r];
#pragma unroll
            for (int yt = 0; yt < 4; ++yt) {
                float v = __expf(2.f * acc[xt][yt][r] - nx - ny[yt]);
                out[(size_t)xr * N + Y0 + 16 * yt + c16] = v;
            }
        }
}

// ---------------------------------------------------------------------------
extern "C" void kernel_launch(void* const* d_in, const int* in_sizes, int n_in,
                              void* d_out, int out_size, void* d_ws, size_t ws_size,
                              hipStream_t stream) {
    const float* Wq = (const float*)d_in[0];
    const float* Wk = (const float*)d_in[1];
    const float* x  = (const float*)d_in[2];
    const float* y  = (const float*)d_in[3];
    float* out = (float*)d_out;

    char* p = (char*)d_ws;
    auto alloc = [&](size_t bytes) -> void* {
        void* r = (void*)p;
        p += (bytes + 255) & ~(size_t)255;
        return r;
    };
    float*  Qx    = (float*) alloc((size_t)N * D * 4);
    float*  Qy    = (float*) alloc((size_t)N * D * 4);
    half_t* Khix  = (half_t*)alloc((size_t)N * D * 2);
    half_t* Klox  = (half_t*)alloc((size_t)N * D * 2);
    half_t* Khiy  = (half_t*)alloc((size_t)N * D * 2);
    half_t* Kloy  = (half_t*)alloc((size_t)N * D * 2);
    half_t* zthix = (half_t*)alloc((size_t)N * D * 2);
    half_t* ztlox = (half_t*)alloc((size_t)N * D * 2);
    half_t* zthiy = (half_t*)alloc((size_t)N * D * 2);
    half_t* ztloy = (half_t*)alloc((size_t)N * D * 2);
    float*  Opart = (float*) alloc((size_t)2 * KSPLIT * N * D * 4);
    float*  mpart = (float*) alloc((size_t)2 * KSPLIT * N * 4);
    float*  lpart = (float*) alloc((size_t)2 * KSPLIT * N * 4);
    half_t* xahi  = (half_t*)alloc((size_t)N * D * 2);
    half_t* xalo  = (half_t*)alloc((size_t)N * D * 2);
    half_t* yahi  = (half_t*)alloc((size_t)N * D * 2);
    half_t* yalo  = (half_t*)alloc((size_t)N * D * 2);
    float*  n2x   = (float*) alloc((size_t)N * 4);
    float*  n2y   = (float*) alloc((size_t)N * 4);

    proj_kernel<<<dim3(2 * N / 16), 256, 0, stream>>>(Wq, Wk, x, y, Qx, Qy,
                                                      Khix, Klox, Khiy, Kloy);
    ztprep_kernel<<<dim3(N / 64, 2), 256, 0, stream>>>(x, y, zthix, ztlox, zthiy, ztloy);
    attn_kernel<<<dim3(N / 128, 2, KSPLIT), 256, 0, stream>>>(
        Qx, Qy, Khix, Klox, Khiy, Kloy, zthix, ztlox, zthiy, ztloy,
        Opart, mpart, lpart);
    combine_kernel<<<dim3(N / 16, 2), 256, 0, stream>>>(
        Opart, mpart, lpart, xahi, xalo, yahi, yalo, n2x, n2y);
    rbf_kernel<<<dim3(N / 128, N / 128), 256, 0, stream>>>(
        xahi, xalo, yahi, yalo, n2x, n2y, out);
}

// Round 4
// 554.842 us; speedup vs baseline: 1.3581x; 1.3581x over previous
//
#include <hip/hip_runtime.h>
#include <math.h>

#define N 8192
#define D 64
#define KSPLIT 4
#define LOG2E 1.4426950408889634f

typedef _Float16 half_t;
typedef _Float16 f16x8 __attribute__((ext_vector_type(8)));
typedef _Float16 f16x4 __attribute__((ext_vector_type(4)));
typedef float f32x4 __attribute__((ext_vector_type(4)));

#define MFMA32(a, b, c) __builtin_amdgcn_mfma_f32_16x16x32_f16((a), (b), (c), 0, 0, 0)

// split a f32 into f16 hi + f16 lo (v ~= hi + lo, rel err ~2^-22)
#define SPLIT(v, H, L) { half_t _h = (half_t)(v); (H) = _h; (L) = (half_t)((v) - (float)_h); }

// ---------------------------------------------------------------------------
// K1: Q = (X@Wq)*0.125*log2e (exp2-domain scores), K = X@Wk as f16 hi/lo.
// ---------------------------------------------------------------------------
__global__ __launch_bounds__(256) void proj_kernel(
    const float* __restrict__ Wq, const float* __restrict__ Wk,
    const float* __restrict__ X, const float* __restrict__ Y,
    float* __restrict__ Qx, float* __restrict__ Qy,
    half_t* __restrict__ Khix, half_t* __restrict__ Klox,
    half_t* __restrict__ Khiy, half_t* __restrict__ Kloy)
{
    __shared__ float sWq[64][64];
    __shared__ float sWk[64][64];
    __shared__ float sIn[16][64];
    const int t = threadIdx.x;
#pragma unroll
    for (int p = 0; p < 16; ++p) {
        int idx = p * 256 + t;
        sWq[idx >> 6][idx & 63] = Wq[idx];
        sWk[idx >> 6][idx & 63] = Wk[idx];
    }
    const int R0 = blockIdx.x * 16;
    const float* src; float* dq; half_t* dkh; half_t* dkl; int r0;
    if (R0 < N) { src = X; dq = Qx; dkh = Khix; dkl = Klox; r0 = R0; }
    else        { src = Y; dq = Qy; dkh = Khiy; dkl = Kloy; r0 = R0 - N; }
#pragma unroll
    for (int p = 0; p < 4; ++p) {
        int idx = p * 256 + t;
        sIn[idx >> 6][idx & 63] = src[(size_t)r0 * D + idx];
    }
    __syncthreads();
    const int c = t & 63;
    const int rb = t >> 6;
#pragma unroll
    for (int rr = 0; rr < 4; ++rr) {
        int r = rr * 4 + rb;
        float aq = 0.f, ak = 0.f;
#pragma unroll
        for (int k = 0; k < 64; ++k) {
            float xv = sIn[r][k];
            aq = fmaf(xv, sWq[k][c], aq);
            ak = fmaf(xv, sWk[k][c], ak);
        }
        dq[(size_t)(r0 + r) * D + c] = aq * (0.125f * LOG2E);
        half_t hh = (half_t)ak;
        dkh[(size_t)(r0 + r) * D + c] = hh;
        dkl[(size_t)(r0 + r) * D + c] = (half_t)(ak - (float)hh);
    }
}

// ---------------------------------------------------------------------------
// K2: zt prep: zt[d][row] = f16 hi/lo of input[row][d] (transposed, split).
// ---------------------------------------------------------------------------
__global__ __launch_bounds__(256) void ztprep_kernel(
    const float* __restrict__ X, const float* __restrict__ Y,
    half_t* __restrict__ zthix, half_t* __restrict__ ztlox,
    half_t* __restrict__ zthiy, half_t* __restrict__ ztloy)
{
    __shared__ float T[64][68];   // [d][r]
    const int t = threadIdx.x;
    const float* src = blockIdx.y ? Y : X;
    half_t* dh = blockIdx.y ? zthiy : zthix;
    half_t* dl = blockIdx.y ? ztloy : ztlox;
    const int r0 = blockIdx.x * 64;
#pragma unroll
    for (int p = 0; p < 4; ++p) {
        int r = p * 16 + (t >> 4);
        int c4 = (t & 15) * 4;
        f32x4 v = *(const f32x4*)&src[(size_t)(r0 + r) * D + c4];
        T[c4 + 0][r] = v[0]; T[c4 + 1][r] = v[1];
        T[c4 + 2][r] = v[2]; T[c4 + 3][r] = v[3];
    }
    __syncthreads();
    const int d = t >> 2, cb = (t & 3) * 16;
    f16x8 h0, h1, l0, l1;
#pragma unroll
    for (int i = 0; i < 8; ++i) { float v = T[d][cb + i];     SPLIT(v, h0[i], l0[i]); }
#pragma unroll
    for (int i = 0; i < 8; ++i) { float v = T[d][cb + 8 + i]; SPLIT(v, h1[i], l1[i]); }
    *(f16x8*)&dh[(size_t)d * N + r0 + cb]     = h0;
    *(f16x8*)&dh[(size_t)d * N + r0 + cb + 8] = h1;
    *(f16x8*)&dl[(size_t)d * N + r0 + cb]     = l0;
    *(f16x8*)&dl[(size_t)d * N + r0 + cb + 8] = l1;
}

// ---------------------------------------------------------------------------
// K3: flash attention, MFMA f16 3-product, software-pipelined.
// Body(t): load Z_t; prefetch K_{t+1} (ping-pong regs); softmax(st_t) in exp2
// domain; P -> per-wave LDS -> B-frags; PV_t (16x16x32); l via ones-row MFMA;
// S_{t+1}. No __syncthreads. grid (64, 2, KSPLIT), 4 waves x 32 q.
// ---------------------------------------------------------------------------
__global__ __launch_bounds__(256, 2) void attn_kernel(
    const float* __restrict__ Qx, const float* __restrict__ Qy,
    const half_t* __restrict__ Khix, const half_t* __restrict__ Klox,
    const half_t* __restrict__ Khiy, const half_t* __restrict__ Kloy,
    const half_t* __restrict__ zthix, const half_t* __restrict__ ztlox,
    const half_t* __restrict__ zthiy, const half_t* __restrict__ ztloy,
    float* __restrict__ Opart, float* __restrict__ mpart, float* __restrict__ lpart)
{
    const int side = blockIdx.y;
    const float*  Q   = side ? Qy    : Qx;
    const half_t* Khi = side ? Khiy  : Khix;
    const half_t* Klo = side ? Kloy  : Klox;
    const half_t* Zhi = side ? zthiy : zthix;
    const half_t* Zlo = side ? ztloy : ztlox;
    const int t = threadIdx.x, w = t >> 6, lane = t & 63;
    const int c16 = lane & 15, quad = lane >> 4;
    const int q0 = blockIdx.x * 128 + w * 32;
    const int kvbase = blockIdx.z * (N / KSPLIT);
    const int ITERS = (N / KSPLIT) / 32;   // 64

    __shared__ half_t Pbuf[4][2][32][40];   // [wave][hi/lo][q][kv(+pad)]
    half_t (*Phi)[40] = Pbuf[w][0];
    half_t (*Plo)[40] = Pbuf[w][1];

    // Q fragments (B-operand: n=lane&15=q, k=quad*8+j)
    f16x8 qh[2][2], ql[2][2];   // [qg][ks]
#pragma unroll
    for (int qg = 0; qg < 2; ++qg)
#pragma unroll
        for (int ks = 0; ks < 2; ++ks) {
            const float* s = &Q[(size_t)(q0 + 16 * qg + c16) * D + ks * 32 + quad * 8];
            f32x4 v0 = *(const f32x4*)s;
            f32x4 v1 = *(const f32x4*)(s + 4);
            f16x8 h, l;
#pragma unroll
            for (int i = 0; i < 4; ++i) { SPLIT(v0[i], h[i],     l[i]); }
#pragma unroll
            for (int i = 0; i < 4; ++i) { SPLIT(v1[i], h[4 + i], l[4 + i]); }
            qh[qg][ks] = h; ql[qg][ks] = l;
        }

    f32x4 ot[4][2] = {};      // O^T accumulators [dt][qg]
    f32x4 lacc[2] = {};       // l accumulators via ones-row MFMA
    float m_run[2] = {-INFINITY, -INFINITY};
    f16x8 ones;
#pragma unroll
    for (int i = 0; i < 8; ++i) ones[i] = (half_t)1.0f;

    f16x8 kAh[2][2], kAl[2][2], kBh[2][2], kBl[2][2];   // ping-pong K frags
    f32x4 st[2][2];                                      // S^T [qg][tau]

    auto loadK = [&](int kv0, f16x8 (&kh)[2][2], f16x8 (&kl)[2][2]) {
#pragma unroll
        for (int ks = 0; ks < 2; ++ks)
#pragma unroll
            for (int tau = 0; tau < 2; ++tau) {
                size_t ko = (size_t)(kv0 + 16 * tau + c16) * D + ks * 32 + quad * 8;
                kh[ks][tau] = *(const f16x8*)&Khi[ko];
                kl[ks][tau] = *(const f16x8*)&Klo[ko];
            }
    };
    auto doS = [&](f16x8 (&kh)[2][2], f16x8 (&kl)[2][2]) {
        const f32x4 zero = {};
#pragma unroll
        for (int qg = 0; qg < 2; ++qg)
#pragma unroll
            for (int tau = 0; tau < 2; ++tau) st[qg][tau] = zero;
#pragma unroll
        for (int ks = 0; ks < 2; ++ks)
#pragma unroll
            for (int tau = 0; tau < 2; ++tau)
#pragma unroll
                for (int qg = 0; qg < 2; ++qg) {
                    st[qg][tau] = MFMA32(kh[ks][tau], qh[qg][ks], st[qg][tau]);
                    st[qg][tau] = MFMA32(kh[ks][tau], ql[qg][ks], st[qg][tau]);
                    st[qg][tau] = MFMA32(kl[ks][tau], qh[qg][ks], st[qg][tau]);
                }
    };

    auto body = [&](int tt, f16x8 (&kh2)[2][2], f16x8 (&kl2)[2][2]) {
        const int kv0 = kvbase + tt * 32;
        // Z_t loads (consumed in PV after softmax -> latency hidden)
        f16x8 zh[4], zl[4];
#pragma unroll
        for (int dt = 0; dt < 4; ++dt) {
            size_t zo = (size_t)(16 * dt + c16) * N + kv0 + quad * 8;
            zh[dt] = *(const f16x8*)&Zhi[zo];
            zl[dt] = *(const f16x8*)&Zlo[zo];
        }
        const bool more = (tt + 1 < ITERS);
        if (more) loadK(kv0 + 32, kh2, kl2);   // prefetch K_{t+1}
        // ---- online softmax (exp2 domain) ----
#pragma unroll
        for (int qg = 0; qg < 2; ++qg) {
            float mt = fmaxf(fmaxf(fmaxf(st[qg][0][0], st[qg][0][1]),
                                   fmaxf(st[qg][0][2], st[qg][0][3])),
                             fmaxf(fmaxf(st[qg][1][0], st[qg][1][1]),
                                   fmaxf(st[qg][1][2], st[qg][1][3])));
            mt = fmaxf(mt, __shfl_xor(mt, 16));
            mt = fmaxf(mt, __shfl_xor(mt, 32));
            float mn = fmaxf(m_run[qg], mt);
            float al = exp2f(m_run[qg] - mn);
            m_run[qg] = mn;
#pragma unroll
            for (int tau = 0; tau < 2; ++tau) {
                f16x4 h4, l4;
#pragma unroll
                for (int r = 0; r < 4; ++r) {
                    float e = exp2f(st[qg][tau][r] - mn);
                    SPLIT(e, h4[r], l4[r]);
                }
                *(f16x4*)&Phi[16 * qg + c16][16 * tau + 4 * quad] = h4;
                *(f16x4*)&Plo[16 * qg + c16][16 * tau + 4 * quad] = l4;
            }
            lacc[qg] *= al;
#pragma unroll
            for (int dt = 0; dt < 4; ++dt) ot[dt][qg] *= al;
        }
        // ---- P B-frags from LDS ----
        f16x8 pbh[2], pbl[2];
#pragma unroll
        for (int qg = 0; qg < 2; ++qg) {
            pbh[qg] = *(const f16x8*)&Phi[16 * qg + c16][quad * 8];
            pbl[qg] = *(const f16x8*)&Plo[16 * qg + c16][quad * 8];
        }
        // ---- PV (16x16x32) + l via ones-row ----
#pragma unroll
        for (int dt = 0; dt < 4; ++dt)
#pragma unroll
            for (int qg = 0; qg < 2; ++qg) {
                ot[dt][qg] = MFMA32(zh[dt], pbh[qg], ot[dt][qg]);
                ot[dt][qg] = MFMA32(zh[dt], pbl[qg], ot[dt][qg]);
                ot[dt][qg] = MFMA32(zl[dt], pbh[qg], ot[dt][qg]);
            }
#pragma unroll
        for (int qg = 0; qg < 2; ++qg) {
            lacc[qg] = MFMA32(ones, pbh[qg], lacc[qg]);
            lacc[qg] = MFMA32(ones, pbl[qg], lacc[qg]);
        }
        // ---- S_{t+1} ----
        if (more) doS(kh2, kl2);
    };

    loadK(kvbase, kAh, kAl);
    doS(kAh, kAl);
#pragma unroll 1
    for (int tt = 0; tt < ITERS; tt += 2) {
        body(tt,     kBh, kBl);
        body(tt + 1, kAh, kAl);
    }

    // epilogue: unnormalized O + m (log2 domain), l partials
    const size_t obase = (size_t)(side * KSPLIT + blockIdx.z) * N;
#pragma unroll
    for (int qg = 0; qg < 2; ++qg) {
        int q = q0 + 16 * qg + c16;
#pragma unroll
        for (int dt = 0; dt < 4; ++dt)
            *(f32x4*)&Opart[(obase + q) * D + 16 * dt + 4 * quad] = ot[dt][qg];
        if (quad == 0) {
            mpart[obase + q] = m_run[qg];
            lpart[obase + q] = lacc[qg][0];
        }
    }
}

// ---------------------------------------------------------------------------
// K4: combine split-K partials -> xa/ya (f16 hi/lo, x side pre-scaled by
// 2*log2e for exp2-domain RBF) + row norms scaled by log2e.
// ---------------------------------------------------------------------------
__global__ __launch_bounds__(256) void combine_kernel(
    const float* __restrict__ Opart, const float* __restrict__ mpart,
    const float* __restrict__ lpart,
    half_t* __restrict__ xahi, half_t* __restrict__ xalo,
    half_t* __restrict__ yahi, half_t* __restrict__ yalo,
    float* __restrict__ n2x, float* __restrict__ n2y)
{
    const int side = blockIdx.y;
    const int q = blockIdx.x * 16 + (threadIdx.x >> 4);
    const int d4 = (threadIdx.x & 15) * 4;
    float m[KSPLIT], l[KSPLIT];
#pragma unroll
    for (int s = 0; s < KSPLIT; ++s) {
        size_t b = (size_t)(side * KSPLIT + s) * N + q;
        m[s] = mpart[b]; l[s] = lpart[b];
    }
    float M = -INFINITY;
#pragma unroll
    for (int s = 0; s < KSPLIT; ++s) M = fmaxf(M, m[s]);
    float L = 0.f;
    f32x4 o = {0.f, 0.f, 0.f, 0.f};
#pragma unroll
    for (int s = 0; s < KSPLIT; ++s) {
        float sc = exp2f(m[s] - M);
        L += l[s] * sc;
        f32x4 p = *(const f32x4*)&Opart[((size_t)(side * KSPLIT + s) * N + q) * D + d4];
        o += p * sc;
    }
    float inv = 1.f / L;
    o *= inv;
    float sq = o[0] * o[0] + o[1] * o[1] + o[2] * o[2] + o[3] * o[3];
#pragma unroll
    for (int off = 1; off < 16; off <<= 1) sq += __shfl_xor(sq, off);
    half_t* dh = side ? yahi : xahi;
    half_t* dl = side ? yalo : xalo;
    float*  n2 = side ? n2y  : n2x;
    if ((threadIdx.x & 15) == 0) n2[q] = sq * LOG2E;
    const float oscale = side ? 1.0f : 2.0f * LOG2E;   // exp2-domain dot on x side
    f16x4 h4, l4;
#pragma unroll
    for (int i = 0; i < 4; ++i) { float v = o[i] * oscale; SPLIT(v, h4[i], l4[i]); }
    *(f16x4*)&dh[(size_t)q * D + d4] = h4;
    *(f16x4*)&dl[(size_t)q * D + d4] = l4;
}

// ---------------------------------------------------------------------------
// K5: RBF via MFMA, frags straight from global (L2). out = exp2(dot' - nx' - ny')
// with dot' = 2*log2e*dot (xa pre-scaled), n' = log2e*|.|^2.
// ---------------------------------------------------------------------------
__global__ __launch_bounds__(256, 3) void rbf_kernel(
    const half_t* __restrict__ xahi, const half_t* __restrict__ xalo,
    const half_t* __restrict__ yahi, const half_t* __restrict__ yalo,
    const float* __restrict__ n2x, const float* __restrict__ n2y,
    float* __restrict__ out)
{
    const int t = threadIdx.x, w = t >> 6, lane = t & 63;
    const int c16 = lane & 15, quad = lane >> 4;
    const int X0 = blockIdx.y * 128 + (w >> 1) * 64;
    const int Y0 = blockIdx.x * 128 + (w & 1) * 64;
    float ny[4];
    f32x4 nx4[4];
#pragma unroll
    for (int yt = 0; yt < 4; ++yt) ny[yt] = n2y[Y0 + 16 * yt + c16];
#pragma unroll
    for (int xt = 0; xt < 4; ++xt)
        nx4[xt] = *(const f32x4*)&n2x[X0 + 16 * xt + 4 * quad];

    f32x4 acc[4][4] = {};   // [xt][yt]
#pragma unroll
    for (int ks = 0; ks < 2; ++ks) {
        f16x8 bh[4], bl[4];
#pragma unroll
        for (int yt = 0; yt < 4; ++yt) {
            size_t off = (size_t)(Y0 + 16 * yt + c16) * D + ks * 32 + quad * 8;
            bh[yt] = *(const f16x8*)&yahi[off];
            bl[yt] = *(const f16x8*)&yalo[off];
        }
#pragma unroll
        for (int xt = 0; xt < 4; ++xt) {
            size_t ao = (size_t)(X0 + 16 * xt + c16) * D + ks * 32 + quad * 8;
            f16x8 ah = *(const f16x8*)&xahi[ao];
            f16x8 al = *(const f16x8*)&xalo[ao];
#pragma unroll
            for (int yt = 0; yt < 4; ++yt) {
                acc[xt][yt] = MFMA32(ah, bh[yt], acc[xt][yt]);
                acc[xt][yt] = MFMA32(ah, bl[yt], acc[xt][yt]);
                acc[xt][yt] = MFMA32(al, bh[yt], acc[xt][yt]);
            }
        }
    }
#pragma unroll
    for (int xt = 0; xt < 4; ++xt)
#pragma unroll
        for (int r = 0; r < 4; ++r) {
            int xr = X0 + 16 * xt + 4 * quad + r;
            float nx = nx4[xt][r];
#pragma unroll
            for (int yt = 0; yt < 4; ++yt) {
                float v = exp2f(acc[xt][yt][r] - nx - ny[yt]);
                out[(size_t)xr * N + Y0 + 16 * yt + c16] = v;
            }
        }
}

// ---------------------------------------------------------------------------
extern "C" void kernel_launch(void* const* d_in, const int* in_sizes, int n_in,
                              void* d_out, int out_size, void* d_ws, size_t ws_size,
                              hipStream_t stream) {
    const float* Wq = (const float*)d_in[0];
    const float* Wk = (const float*)d_in[1];
    const float* x  = (const float*)d_in[2];
    const float* y  = (const float*)d_in[3];
    float* out = (float*)d_out;

    char* p = (char*)d_ws;
    auto alloc = [&](size_t bytes) -> void* {
        void* r = (void*)p;
        p += (bytes + 255) & ~(size_t)255;
        return r;
    };
    float*  Qx    = (float*) alloc((size_t)N * D * 4);
    float*  Qy    = (float*) alloc((size_t)N * D * 4);
    half_t* Khix  = (half_t*)alloc((size_t)N * D * 2);
    half_t* Klox  = (half_t*)alloc((size_t)N * D * 2);
    half_t* Khiy  = (half_t*)alloc((size_t)N * D * 2);
    half_t* Kloy  = (half_t*)alloc((size_t)N * D * 2);
    half_t* zthix = (half_t*)alloc((size_t)N * D * 2);
    half_t* ztlox = (half_t*)alloc((size_t)N * D * 2);
    half_t* zthiy = (half_t*)alloc((size_t)N * D * 2);
    half_t* ztloy = (half_t*)alloc((size_t)N * D * 2);
    float*  Opart = (float*) alloc((size_t)2 * KSPLIT * N * D * 4);
    float*  mpart = (float*) alloc((size_t)2 * KSPLIT * N * 4);
    float*  lpart = (float*) alloc((size_t)2 * KSPLIT * N * 4);
    half_t* xahi  = (half_t*)alloc((size_t)N * D * 2);
    half_t* xalo  = (half_t*)alloc((size_t)N * D * 2);
    half_t* yahi  = (half_t*)alloc((size_t)N * D * 2);
    half_t* yalo  = (half_t*)alloc((size_t)N * D * 2);
    float*  n2x   = (float*) alloc((size_t)N * 4);
    float*  n2y   = (float*) alloc((size_t)N * 4);

    proj_kernel<<<dim3(2 * N / 16), 256, 0, stream>>>(Wq, Wk, x, y, Qx, Qy,
                                                      Khix, Klox, Khiy, Kloy);
    ztprep_kernel<<<dim3(N / 64, 2), 256, 0, stream>>>(x, y, zthix, ztlox, zthiy, ztloy);
    attn_kernel<<<dim3(N / 128, 2, KSPLIT), 256, 0, stream>>>(
        Qx, Qy, Khix, Klox, Khiy, Kloy, zthix, ztlox, zthiy, ztloy,
        Opart, mpart, lpart);
    combine_kernel<<<dim3(N / 16, 2), 256, 0, stream>>>(
        Opart, mpart, lpart, xahi, xalo, yahi, yalo, n2x, n2y);
    rbf_kernel<<<dim3(N / 128, N / 128), 256, 0, stream>>>(
        xahi, xalo, yahi, yalo, n2x, n2y, out);
}

// Round 5
// 452.936 us; speedup vs baseline: 1.6637x; 1.2250x over previous
//
#include <hip/hip_runtime.h>
#include <math.h>

#define N 8192
#define D 64
#define LOG2E 1.4426950408889634f

typedef _Float16 half_t;
typedef _Float16 f16x8 __attribute__((ext_vector_type(8)));
typedef _Float16 f16x4 __attribute__((ext_vector_type(4)));
typedef float f32x4 __attribute__((ext_vector_type(4)));

#define MFMA32(a, b, c) __builtin_amdgcn_mfma_f32_16x16x32_f16((a), (b), (c), 0, 0, 0)

// split a f32 into f16 hi + f16 lo (v ~= hi + lo, rel err ~2^-22)
#define SPLIT(v, H, L) { half_t _h = (half_t)(v); (H) = _h; (L) = (half_t)((v) - (float)_h); }

// Fragment-major layouts (all loads in hot loops become base + lane*16B):
//  Kf  [tile32][ks][tau][hl][lane][8] : elem (row=tile*32+tau*16+c16, col=ks*32+quad*8+j)
//       offset = tile*4096 + ks*2048 + tau*1024 + hl*512 + lane*8 + j
//  Zf  [tile32][dt][hl][lane][8]      : elem (row=tile*32+quad*8+j, d=dt*16+c16)  (transposed)
//       offset = tile*4096 + dt*1024 + hl*512 + lane*8 + j
//  XYf [tile16][ks][hl][lane][8]      : elem (row=tile*16+c16, col=ks*32+quad*8+j)
//       offset = tile*2048 + ks*1024 + hl*512 + lane*8 + j
// where lane = quad*16 + c16.

// ---------------------------------------------------------------------------
// K1: Q = (X@Wq)*0.125*log2e (f32 row-major), K = X@Wk -> Kf frag-major hi/lo.
// ---------------------------------------------------------------------------
__global__ __launch_bounds__(256) void proj_kernel(
    const float* __restrict__ Wq, const float* __restrict__ Wk,
    const float* __restrict__ X, const float* __restrict__ Y,
    float* __restrict__ Qx, float* __restrict__ Qy,
    half_t* __restrict__ Kfx, half_t* __restrict__ Kfy)
{
    __shared__ float sWq[64][64];
    __shared__ float sWk[64][64];
    __shared__ float sIn[16][64];
    const int t = threadIdx.x;
#pragma unroll
    for (int p = 0; p < 16; ++p) {
        int idx = p * 256 + t;
        sWq[idx >> 6][idx & 63] = Wq[idx];
        sWk[idx >> 6][idx & 63] = Wk[idx];
    }
    const int R0 = blockIdx.x * 16;
    const float* src; float* dq; half_t* dkf; int r0;
    if (R0 < N) { src = X; dq = Qx; dkf = Kfx; r0 = R0; }
    else        { src = Y; dq = Qy; dkf = Kfy; r0 = R0 - N; }
#pragma unroll
    for (int p = 0; p < 4; ++p) {
        int idx = p * 256 + t;
        sIn[idx >> 6][idx & 63] = src[(size_t)r0 * D + idx];
    }
    __syncthreads();
    const int c = t & 63;
    const int rb = t >> 6;
    const int ksi = c >> 5, quadi = (c >> 3) & 3, j = c & 7;
#pragma unroll
    for (int rr = 0; rr < 4; ++rr) {
        int r = rr * 4 + rb;
        float aq = 0.f, ak = 0.f;
#pragma unroll
        for (int k = 0; k < 64; ++k) {
            float xv = sIn[r][k];
            aq = fmaf(xv, sWq[k][c], aq);
            ak = fmaf(xv, sWk[k][c], ak);
        }
        int rg = r0 + r;
        dq[(size_t)rg * D + c] = aq * (0.125f * LOG2E);
        int tile = rg >> 5, tau = (rg >> 4) & 1, c16l = rg & 15;
        size_t kidx = (size_t)tile * 4096 + ksi * 2048 + tau * 1024
                    + (quadi * 16 + c16l) * 8 + j;
        half_t hh = (half_t)ak;
        dkf[kidx]       = hh;
        dkf[kidx + 512] = (half_t)(ak - (float)hh);
    }
}

// ---------------------------------------------------------------------------
// K2: Zf prep (transposed input, f16 hi/lo, frag-major). grid (N/32, 2).
// ---------------------------------------------------------------------------
__global__ __launch_bounds__(256) void ztprep_kernel(
    const float* __restrict__ X, const float* __restrict__ Y,
    half_t* __restrict__ Zfx, half_t* __restrict__ Zfy)
{
    const int t = threadIdx.x;
    const int tile = blockIdx.x;
    const float* src = blockIdx.y ? Y : X;
    half_t* dst = blockIdx.y ? Zfy : Zfx;
    const int dt = t >> 6, lane = t & 63;
    const int quad = lane >> 4, c16 = lane & 15;
    f16x8 h, l;
#pragma unroll
    for (int j = 0; j < 8; ++j) {
        float v = src[(size_t)(tile * 32 + quad * 8 + j) * D + dt * 16 + c16];
        SPLIT(v, h[j], l[j]);
    }
    half_t* d = dst + (size_t)tile * 4096 + dt * 1024 + lane * 8;
    *(f16x8*)&d[0]   = h;
    *(f16x8*)&d[512] = l;
}

// ---------------------------------------------------------------------------
// K3: flash attention, MFMA f16 3-product, software-pipelined, frag-major
// global loads (fully coalesced). Per-wave LDS P round-trip; l via ones-MFMA;
// exp2 domain. grid (N/128, 2, KS), 4 waves x 32 q.
// ---------------------------------------------------------------------------
template<int KS>
__global__ __launch_bounds__(256, 2) void attn_kernel(
    const float* __restrict__ Qx, const float* __restrict__ Qy,
    const half_t* __restrict__ Kfx, const half_t* __restrict__ Kfy,
    const half_t* __restrict__ Zfx, const half_t* __restrict__ Zfy,
    float* __restrict__ Opart, float* __restrict__ mpart, float* __restrict__ lpart)
{
    const int side = blockIdx.y;
    const float*  Q  = side ? Qy  : Qx;
    const half_t* Kf = side ? Kfy : Kfx;
    const half_t* Zf = side ? Zfy : Zfx;
    const int t = threadIdx.x, w = t >> 6, lane = t & 63;
    const int c16 = lane & 15, quad = lane >> 4;
    const int q0 = blockIdx.x * 128 + w * 32;
    const int tile0 = blockIdx.z * (N / KS / 32);
    const int ITERS = (N / KS) / 32;

    __shared__ half_t Pbuf[4][2][32][40];   // [wave][hi/lo][q][kv(+pad)]
    half_t (*Phi)[40] = Pbuf[w][0];
    half_t (*Plo)[40] = Pbuf[w][1];

    // Q fragments (B-operand: n=lane&15=q, k=quad*8+j)
    f16x8 qh[2][2], ql[2][2];   // [qg][ks]
#pragma unroll
    for (int qg = 0; qg < 2; ++qg)
#pragma unroll
        for (int ks = 0; ks < 2; ++ks) {
            const float* s = &Q[(size_t)(q0 + 16 * qg + c16) * D + ks * 32 + quad * 8];
            f32x4 v0 = *(const f32x4*)s;
            f32x4 v1 = *(const f32x4*)(s + 4);
            f16x8 h, l;
#pragma unroll
            for (int i = 0; i < 4; ++i) { SPLIT(v0[i], h[i],     l[i]); }
#pragma unroll
            for (int i = 0; i < 4; ++i) { SPLIT(v1[i], h[4 + i], l[4 + i]); }
            qh[qg][ks] = h; ql[qg][ks] = l;
        }

    f32x4 ot[4][2] = {};      // O^T accumulators [dt][qg]
    f32x4 lacc[2] = {};       // l accumulators via ones-row MFMA
    float m_run[2] = {-INFINITY, -INFINITY};
    f16x8 ones;
#pragma unroll
    for (int i = 0; i < 8; ++i) ones[i] = (half_t)1.0f;

    f16x8 kAh[2][2], kAl[2][2], kBh[2][2], kBl[2][2];   // ping-pong K frags
    f32x4 st[2][2];                                      // S^T [qg][tau]

    auto loadK = [&](int tile, f16x8 (&kh)[2][2], f16x8 (&kl)[2][2]) {
        const half_t* b = Kf + (size_t)tile * 4096 + lane * 8;
#pragma unroll
        for (int ks = 0; ks < 2; ++ks)
#pragma unroll
            for (int tau = 0; tau < 2; ++tau) {
                kh[ks][tau] = *(const f16x8*)&b[ks * 2048 + tau * 1024];
                kl[ks][tau] = *(const f16x8*)&b[ks * 2048 + tau * 1024 + 512];
            }
    };
    auto doS = [&](f16x8 (&kh)[2][2], f16x8 (&kl)[2][2]) {
        const f32x4 zero = {};
#pragma unroll
        for (int qg = 0; qg < 2; ++qg)
#pragma unroll
            for (int tau = 0; tau < 2; ++tau) st[qg][tau] = zero;
#pragma unroll
        for (int ks = 0; ks < 2; ++ks)
#pragma unroll
            for (int tau = 0; tau < 2; ++tau)
#pragma unroll
                for (int qg = 0; qg < 2; ++qg) {
                    st[qg][tau] = MFMA32(kh[ks][tau], qh[qg][ks], st[qg][tau]);
                    st[qg][tau] = MFMA32(kh[ks][tau], ql[qg][ks], st[qg][tau]);
                    st[qg][tau] = MFMA32(kl[ks][tau], qh[qg][ks], st[qg][tau]);
                }
    };

    auto body = [&](int tt, f16x8 (&kh2)[2][2], f16x8 (&kl2)[2][2]) {
        const int tile = tile0 + tt;
        // Z_t loads (consumed in PV after softmax -> latency hidden)
        const half_t* zb = Zf + (size_t)tile * 4096 + lane * 8;
        f16x8 zh[4], zl[4];
#pragma unroll
        for (int dt = 0; dt < 4; ++dt) {
            zh[dt] = *(const f16x8*)&zb[dt * 1024];
            zl[dt] = *(const f16x8*)&zb[dt * 1024 + 512];
        }
        const bool more = (tt + 1 < ITERS);
        if (more) loadK(tile + 1, kh2, kl2);   // prefetch K_{t+1}
        // ---- online softmax (exp2 domain) ----
#pragma unroll
        for (int qg = 0; qg < 2; ++qg) {
            float mt = fmaxf(fmaxf(fmaxf(st[qg][0][0], st[qg][0][1]),
                                   fmaxf(st[qg][0][2], st[qg][0][3])),
                             fmaxf(fmaxf(st[qg][1][0], st[qg][1][1]),
                                   fmaxf(st[qg][1][2], st[qg][1][3])));
            mt = fmaxf(mt, __shfl_xor(mt, 16));
            mt = fmaxf(mt, __shfl_xor(mt, 32));
            float mn = fmaxf(m_run[qg], mt);
            float al = exp2f(m_run[qg] - mn);
            m_run[qg] = mn;
#pragma unroll
            for (int tau = 0; tau < 2; ++tau) {
                f16x4 h4, l4;
#pragma unroll
                for (int r = 0; r < 4; ++r) {
                    float e = exp2f(st[qg][tau][r] - mn);
                    SPLIT(e, h4[r], l4[r]);
                }
                *(f16x4*)&Phi[16 * qg + c16][16 * tau + 4 * quad] = h4;
                *(f16x4*)&Plo[16 * qg + c16][16 * tau + 4 * quad] = l4;
            }
            lacc[qg] *= al;
#pragma unroll
            for (int dt = 0; dt < 4; ++dt) ot[dt][qg] *= al;
        }
        // ---- P B-frags from LDS ----
        f16x8 pbh[2], pbl[2];
#pragma unroll
        for (int qg = 0; qg < 2; ++qg) {
            pbh[qg] = *(const f16x8*)&Phi[16 * qg + c16][quad * 8];
            pbl[qg] = *(const f16x8*)&Plo[16 * qg + c16][quad * 8];
        }
        // ---- PV (16x16x32) + l via ones-row ----
#pragma unroll
        for (int dt = 0; dt < 4; ++dt)
#pragma unroll
            for (int qg = 0; qg < 2; ++qg) {
                ot[dt][qg] = MFMA32(zh[dt], pbh[qg], ot[dt][qg]);
                ot[dt][qg] = MFMA32(zh[dt], pbl[qg], ot[dt][qg]);
                ot[dt][qg] = MFMA32(zl[dt], pbh[qg], ot[dt][qg]);
            }
#pragma unroll
        for (int qg = 0; qg < 2; ++qg) {
            lacc[qg] = MFMA32(ones, pbh[qg], lacc[qg]);
            lacc[qg] = MFMA32(ones, pbl[qg], lacc[qg]);
        }
        // ---- S_{t+1} ----
        if (more) doS(kh2, kl2);
    };

    loadK(tile0, kAh, kAl);
    doS(kAh, kAl);
#pragma unroll 1
    for (int tt = 0; tt < ITERS; tt += 2) {
        body(tt,     kBh, kBl);
        body(tt + 1, kAh, kAl);
    }

    // epilogue: unnormalized O + m (log2 domain), l partials
    const size_t obase = (size_t)(side * KS + blockIdx.z) * N;
#pragma unroll
    for (int qg = 0; qg < 2; ++qg) {
        int q = q0 + 16 * qg + c16;
#pragma unroll
        for (int dt = 0; dt < 4; ++dt)
            *(f32x4*)&Opart[(obase + q) * D + 16 * dt + 4 * quad] = ot[dt][qg];
        if (quad == 0) {
            mpart[obase + q] = m_run[qg];
            lpart[obase + q] = lacc[qg][0];
        }
    }
}

// ---------------------------------------------------------------------------
// K4: combine split-K partials -> Xf/Yf (frag-major f16 hi/lo; x side scaled
// by 2*log2e for exp2-domain RBF) + row norms scaled by log2e.
// ---------------------------------------------------------------------------
template<int KS>
__global__ __launch_bounds__(256) void combine_kernel(
    const float* __restrict__ Opart, const float* __restrict__ mpart,
    const float* __restrict__ lpart,
    half_t* __restrict__ Xf, half_t* __restrict__ Yf,
    float* __restrict__ n2x, float* __restrict__ n2y)
{
    const int side = blockIdx.y;
    const int q = blockIdx.x * 16 + (threadIdx.x >> 4);
    const int d4 = (threadIdx.x & 15) * 4;
    float m[KS], l[KS];
#pragma unroll
    for (int s = 0; s < KS; ++s) {
        size_t b = (size_t)(side * KS + s) * N + q;
        m[s] = mpart[b]; l[s] = lpart[b];
    }
    float M = -INFINITY;
#pragma unroll
    for (int s = 0; s < KS; ++s) M = fmaxf(M, m[s]);
    float L = 0.f;
    f32x4 o = {0.f, 0.f, 0.f, 0.f};
#pragma unroll
    for (int s = 0; s < KS; ++s) {
        float sc = exp2f(m[s] - M);
        L += l[s] * sc;
        f32x4 p = *(const f32x4*)&Opart[((size_t)(side * KS + s) * N + q) * D + d4];
        o += p * sc;
    }
    float inv = 1.f / L;
    o *= inv;
    float sq = o[0] * o[0] + o[1] * o[1] + o[2] * o[2] + o[3] * o[3];
#pragma unroll
    for (int off = 1; off < 16; off <<= 1) sq += __shfl_xor(sq, off);
    half_t* dst = side ? Yf : Xf;
    float*  n2  = side ? n2y : n2x;
    if ((threadIdx.x & 15) == 0) n2[q] = sq * LOG2E;
    const float oscale = side ? 1.0f : 2.0f * LOG2E;   // exp2-domain dot on x side
    f16x4 h4, l4;
#pragma unroll
    for (int i = 0; i < 4; ++i) { float v = o[i] * oscale; SPLIT(v, h4[i], l4[i]); }
    const int tile16 = q >> 4, c16l = q & 15;
    const int ksi = d4 >> 5, quadi = (d4 >> 3) & 3, j0 = d4 & 7;
    size_t idx = (size_t)tile16 * 2048 + ksi * 1024 + (quadi * 16 + c16l) * 8 + j0;
    *(f16x4*)&dst[idx]       = h4;
    *(f16x4*)&dst[idx + 512] = l4;
}

// ---------------------------------------------------------------------------
// K5: RBF via MFMA, frag-major coalesced loads. Block = 4 waves (2x2),
// 128x128 tile, 64x64/wave. out = exp2(dot' - nx' - ny').
// ---------------------------------------------------------------------------
__global__ __launch_bounds__(256, 3) void rbf_kernel(
    const half_t* __restrict__ Xf, const half_t* __restrict__ Yf,
    const float* __restrict__ n2x, const float* __restrict__ n2y,
    float* __restrict__ out)
{
    const int t = threadIdx.x, w = t >> 6, lane = t & 63;
    const int c16 = lane & 15, quad = lane >> 4;
    const int X0 = blockIdx.y * 128 + (w >> 1) * 64;
    const int Y0 = blockIdx.x * 128 + (w & 1) * 64;
    float ny[4];
    f32x4 nx4[4];
#pragma unroll
    for (int yt = 0; yt < 4; ++yt) ny[yt] = n2y[Y0 + 16 * yt + c16];
#pragma unroll
    for (int xt = 0; xt < 4; ++xt)
        nx4[xt] = *(const f32x4*)&n2x[X0 + 16 * xt + 4 * quad];

    const half_t* Xb = Xf + lane * 8;
    const half_t* Yb = Yf + lane * 8;
    f32x4 acc[4][4] = {};   // [xt][yt]
#pragma unroll
    for (int ks = 0; ks < 2; ++ks) {
        f16x8 bh[4], bl[4];
#pragma unroll
        for (int yt = 0; yt < 4; ++yt) {
            size_t off = (size_t)((Y0 >> 4) + yt) * 2048 + ks * 1024;
            bh[yt] = *(const f16x8*)&Yb[off];
            bl[yt] = *(const f16x8*)&Yb[off + 512];
        }
#pragma unroll
        for (int xt = 0; xt < 4; ++xt) {
            size_t ao = (size_t)((X0 >> 4) + xt) * 2048 + ks * 1024;
            f16x8 ah = *(const f16x8*)&Xb[ao];
            f16x8 al = *(const f16x8*)&Xb[ao + 512];
#pragma unroll
            for (int yt = 0; yt < 4; ++yt) {
                acc[xt][yt] = MFMA32(ah, bh[yt], acc[xt][yt]);
                acc[xt][yt] = MFMA32(ah, bl[yt], acc[xt][yt]);
                acc[xt][yt] = MFMA32(al, bh[yt], acc[xt][yt]);
            }
        }
    }
#pragma unroll
    for (int xt = 0; xt < 4; ++xt)
#pragma unroll
        for (int r = 0; r < 4; ++r) {
            int xr = X0 + 16 * xt + 4 * quad + r;
            float nx = nx4[xt][r];
#pragma unroll
            for (int yt = 0; yt < 4; ++yt) {
                float v = exp2f(acc[xt][yt][r] - nx - ny[yt]);
                out[(size_t)xr * N + Y0 + 16 * yt + c16] = v;
            }
        }
}

// ---------------------------------------------------------------------------
extern "C" void kernel_launch(void* const* d_in, const int* in_sizes, int n_in,
                              void* d_out, int out_size, void* d_ws, size_t ws_size,
                              hipStream_t stream) {
    const float* Wq = (const float*)d_in[0];
    const float* Wk = (const float*)d_in[1];
    const float* x  = (const float*)d_in[2];
    const float* y  = (const float*)d_in[3];
    float* out = (float*)d_out;

    char* p = (char*)d_ws;
    size_t used = 0;
    auto alloc = [&](size_t bytes) -> void* {
        void* r = (void*)(p + used);
        used += (bytes + 255) & ~(size_t)255;
        return r;
    };
    float*  Qx  = (float*) alloc((size_t)N * D * 4);
    float*  Qy  = (float*) alloc((size_t)N * D * 4);
    half_t* Kfx = (half_t*)alloc((size_t)N * D * 2 * 2);   // hi+lo
    half_t* Kfy = (half_t*)alloc((size_t)N * D * 2 * 2);
    half_t* Zfx = (half_t*)alloc((size_t)N * D * 2 * 2);
    half_t* Zfy = (half_t*)alloc((size_t)N * D * 2 * 2);
    half_t* Xf  = (half_t*)alloc((size_t)N * D * 2 * 2);
    half_t* Yf  = (half_t*)alloc((size_t)N * D * 2 * 2);
    float*  n2x = (float*) alloc((size_t)N * 4);
    float*  n2y = (float*) alloc((size_t)N * 4);

    const size_t base = used;
    const size_t per_split = (size_t)2 * N * D * 4 + (size_t)2 * N * 4 * 2 + 3 * 256;
    const int KS = (ws_size >= base + 8 * per_split) ? 8 : 4;

    float* Opart = (float*)alloc((size_t)2 * KS * N * D * 4);
    float* mpart = (float*)alloc((size_t)2 * KS * N * 4);
    float* lpart = (float*)alloc((size_t)2 * KS * N * 4);

    proj_kernel<<<dim3(2 * N / 16), 256, 0, stream>>>(Wq, Wk, x, y, Qx, Qy, Kfx, Kfy);
    ztprep_kernel<<<dim3(N / 32, 2), 256, 0, stream>>>(x, y, Zfx, Zfy);
    if (KS == 8) {
        attn_kernel<8><<<dim3(N / 128, 2, 8), 256, 0, stream>>>(
            Qx, Qy, Kfx, Kfy, Zfx, Zfy, Opart, mpart, lpart);
        combine_kernel<8><<<dim3(N / 16, 2), 256, 0, stream>>>(
            Opart, mpart, lpart, Xf, Yf, n2x, n2y);
    } else {
        attn_kernel<4><<<dim3(N / 128, 2, 4), 256, 0, stream>>>(
            Qx, Qy, Kfx, Kfy, Zfx, Zfy, Opart, mpart, lpart);
        combine_kernel<4><<<dim3(N / 16, 2), 256, 0, stream>>>(
            Opart, mpart, lpart, Xf, Yf, n2x, n2y);
    }
    rbf_kernel<<<dim3(N / 128, N / 128), 256, 0, stream>>>(Xf, Yf, n2x, n2y, out);
}

// Round 6
// 428.777 us; speedup vs baseline: 1.7575x; 1.0563x over previous
//
#include <hip/hip_runtime.h>
#include <math.h>

#define N 8192
#define D 64
#define LOG2E 1.4426950408889634f

typedef _Float16 half_t;
typedef _Float16 f16x8 __attribute__((ext_vector_type(8)));
typedef _Float16 f16x4 __attribute__((ext_vector_type(4)));
typedef float f32x4 __attribute__((ext_vector_type(4)));

#define MFMA32(a, b, c) __builtin_amdgcn_mfma_f32_16x16x32_f16((a), (b), (c), 0, 0, 0)

// split a f32 into f16 hi + f16 lo (v ~= hi + lo, rel err ~2^-22)
#define SPLIT(v, H, L) { half_t _h = (half_t)(v); (H) = _h; (L) = (half_t)((v) - (float)_h); }

// Fragment-major layouts (all hot-loop loads are base + lane*16B or *8B):
//  Kf  [tile32][ks][tau][hl][lane][8] : elem (row=tile*32+tau*16+c16, col=ks*32+quad*8+j)
//  Zf  [tile32][dt][lane][8]          : elem (row=tile*32+quad*8+j, d=dt*16+c16)  HI ONLY
//  XYf [tile16][ks][hl][lane][8]      : elem (row=tile*16+c16, col=ks*32+quad*8+j)
// where lane = quad*16 + c16.

// ---------------------------------------------------------------------------
// K1: Q = (X@Wq)*0.125*log2e (f32 row-major), K = X@Wk -> Kf frag-major hi/lo.
// ---------------------------------------------------------------------------
__global__ __launch_bounds__(256) void proj_kernel(
    const float* __restrict__ Wq, const float* __restrict__ Wk,
    const float* __restrict__ X, const float* __restrict__ Y,
    float* __restrict__ Qx, float* __restrict__ Qy,
    half_t* __restrict__ Kfx, half_t* __restrict__ Kfy)
{
    __shared__ float sWq[64][64];
    __shared__ float sWk[64][64];
    __shared__ float sIn[16][64];
    const int t = threadIdx.x;
#pragma unroll
    for (int p = 0; p < 16; ++p) {
        int idx = p * 256 + t;
        sWq[idx >> 6][idx & 63] = Wq[idx];
        sWk[idx >> 6][idx & 63] = Wk[idx];
    }
    const int R0 = blockIdx.x * 16;
    const float* src; float* dq; half_t* dkf; int r0;
    if (R0 < N) { src = X; dq = Qx; dkf = Kfx; r0 = R0; }
    else        { src = Y; dq = Qy; dkf = Kfy; r0 = R0 - N; }
#pragma unroll
    for (int p = 0; p < 4; ++p) {
        int idx = p * 256 + t;
        sIn[idx >> 6][idx & 63] = src[(size_t)r0 * D + idx];
    }
    __syncthreads();
    const int c = t & 63;
    const int rb = t >> 6;
    const int ksi = c >> 5, quadi = (c >> 3) & 3, j = c & 7;
#pragma unroll
    for (int rr = 0; rr < 4; ++rr) {
        int r = rr * 4 + rb;
        float aq = 0.f, ak = 0.f;
#pragma unroll
        for (int k = 0; k < 64; ++k) {
            float xv = sIn[r][k];
            aq = fmaf(xv, sWq[k][c], aq);
            ak = fmaf(xv, sWk[k][c], ak);
        }
        int rg = r0 + r;
        dq[(size_t)rg * D + c] = aq * (0.125f * LOG2E);
        int tile = rg >> 5, tau = (rg >> 4) & 1, c16l = rg & 15;
        size_t kidx = (size_t)tile * 4096 + ksi * 2048 + tau * 1024
                    + (quadi * 16 + c16l) * 8 + j;
        half_t hh = (half_t)ak;
        dkf[kidx]       = hh;
        dkf[kidx + 512] = (half_t)(ak - (float)hh);
    }
}

// ---------------------------------------------------------------------------
// K2: Zf prep (transposed input, f16 HI only, frag-major). grid (N/32, 2).
// ---------------------------------------------------------------------------
__global__ __launch_bounds__(256) void ztprep_kernel(
    const float* __restrict__ X, const float* __restrict__ Y,
    half_t* __restrict__ Zfx, half_t* __restrict__ Zfy)
{
    const int t = threadIdx.x;
    const int tile = blockIdx.x;
    const float* src = blockIdx.y ? Y : X;
    half_t* dst = blockIdx.y ? Zfy : Zfx;
    const int dt = t >> 6, lane = t & 63;
    const int quad = lane >> 4, c16 = lane & 15;
    f16x8 h;
#pragma unroll
    for (int j = 0; j < 8; ++j)
        h[j] = (half_t)src[(size_t)(tile * 32 + quad * 8 + j) * D + dt * 16 + c16];
    *(f16x8*)&dst[(size_t)tile * 2048 + dt * 512 + lane * 8] = h;
}

// ---------------------------------------------------------------------------
// K3: flash attention. S = 3-term f16 hi/lo (abs precision needed on scores);
// P and Z are f16 HI-only (only relative precision needed). PV = 8 MFMAs,
// l via ones-row MFMA on P-hi (exactly consistent normalization).
// Software-pipelined K prefetch; frag-major coalesced loads; exp2 domain.
// grid (N/128, 2, KS), 4 waves x 32 q.
// ---------------------------------------------------------------------------
template<int KS>
__global__ __launch_bounds__(256, 2) void attn_kernel(
    const float* __restrict__ Qx, const float* __restrict__ Qy,
    const half_t* __restrict__ Kfx, const half_t* __restrict__ Kfy,
    const half_t* __restrict__ Zfx, const half_t* __restrict__ Zfy,
    float* __restrict__ Opart, float* __restrict__ mpart, float* __restrict__ lpart)
{
    const int side = blockIdx.y;
    const float*  Q  = side ? Qy  : Qx;
    const half_t* Kf = side ? Kfy : Kfx;
    const half_t* Zf = side ? Zfy : Zfx;
    const int t = threadIdx.x, w = t >> 6, lane = t & 63;
    const int c16 = lane & 15, quad = lane >> 4;
    const int q0 = blockIdx.x * 128 + w * 32;
    const int tile0 = blockIdx.z * (N / KS / 32);
    const int ITERS = (N / KS) / 32;

    __shared__ half_t Pbuf[4][32][40];   // [wave][q][kv(+pad)] hi only
    half_t (*Phi)[40] = Pbuf[w];

    // Q fragments (B-operand: n=lane&15=q, k=quad*8+j)
    f16x8 qh[2][2], ql[2][2];   // [qg][ks]
#pragma unroll
    for (int qg = 0; qg < 2; ++qg)
#pragma unroll
        for (int ks = 0; ks < 2; ++ks) {
            const float* s = &Q[(size_t)(q0 + 16 * qg + c16) * D + ks * 32 + quad * 8];
            f32x4 v0 = *(const f32x4*)s;
            f32x4 v1 = *(const f32x4*)(s + 4);
            f16x8 h, l;
#pragma unroll
            for (int i = 0; i < 4; ++i) { SPLIT(v0[i], h[i],     l[i]); }
#pragma unroll
            for (int i = 0; i < 4; ++i) { SPLIT(v1[i], h[4 + i], l[4 + i]); }
            qh[qg][ks] = h; ql[qg][ks] = l;
        }

    f32x4 ot[4][2] = {};      // O^T accumulators [dt][qg]
    f32x4 lacc[2] = {};       // l accumulators via ones-row MFMA
    float m_run[2] = {-INFINITY, -INFINITY};
    f16x8 ones;
#pragma unroll
    for (int i = 0; i < 8; ++i) ones[i] = (half_t)1.0f;

    f16x8 kAh[2][2], kAl[2][2], kBh[2][2], kBl[2][2];   // ping-pong K frags
    f32x4 st[2][2];                                      // S^T [qg][tau]

    auto loadK = [&](int tile, f16x8 (&kh)[2][2], f16x8 (&kl)[2][2]) {
        const half_t* b = Kf + (size_t)tile * 4096 + lane * 8;
#pragma unroll
        for (int ks = 0; ks < 2; ++ks)
#pragma unroll
            for (int tau = 0; tau < 2; ++tau) {
                kh[ks][tau] = *(const f16x8*)&b[ks * 2048 + tau * 1024];
                kl[ks][tau] = *(const f16x8*)&b[ks * 2048 + tau * 1024 + 512];
            }
    };
    auto doS = [&](f16x8 (&kh)[2][2], f16x8 (&kl)[2][2]) {
        const f32x4 zero = {};
#pragma unroll
        for (int qg = 0; qg < 2; ++qg)
#pragma unroll
            for (int tau = 0; tau < 2; ++tau) st[qg][tau] = zero;
#pragma unroll
        for (int ks = 0; ks < 2; ++ks)
#pragma unroll
            for (int tau = 0; tau < 2; ++tau)
#pragma unroll
                for (int qg = 0; qg < 2; ++qg) {
                    st[qg][tau] = MFMA32(kh[ks][tau], qh[qg][ks], st[qg][tau]);
                    st[qg][tau] = MFMA32(kh[ks][tau], ql[qg][ks], st[qg][tau]);
                    st[qg][tau] = MFMA32(kl[ks][tau], qh[qg][ks], st[qg][tau]);
                }
    };

    auto body = [&](int tt, f16x8 (&kh2)[2][2], f16x8 (&kl2)[2][2]) {
        const int tile = tile0 + tt;
        // Z_t loads (hi only; consumed in PV after softmax -> latency hidden)
        const half_t* zb = Zf + (size_t)tile * 2048 + lane * 8;
        f16x8 zh[4];
#pragma unroll
        for (int dt = 0; dt < 4; ++dt)
            zh[dt] = *(const f16x8*)&zb[dt * 512];
        const bool more = (tt + 1 < ITERS);
        if (more) loadK(tile + 1, kh2, kl2);   // prefetch K_{t+1}
        // ---- online softmax (exp2 domain), P hi-only ----
#pragma unroll
        for (int qg = 0; qg < 2; ++qg) {
            float mt = fmaxf(fmaxf(fmaxf(st[qg][0][0], st[qg][0][1]),
                                   fmaxf(st[qg][0][2], st[qg][0][3])),
                             fmaxf(fmaxf(st[qg][1][0], st[qg][1][1]),
                                   fmaxf(st[qg][1][2], st[qg][1][3])));
            mt = fmaxf(mt, __shfl_xor(mt, 16));
            mt = fmaxf(mt, __shfl_xor(mt, 32));
            float mn = fmaxf(m_run[qg], mt);
            float al = exp2f(m_run[qg] - mn);
            m_run[qg] = mn;
#pragma unroll
            for (int tau = 0; tau < 2; ++tau) {
                f16x4 h4;
#pragma unroll
                for (int r = 0; r < 4; ++r)
                    h4[r] = (half_t)exp2f(st[qg][tau][r] - mn);
                *(f16x4*)&Phi[16 * qg + c16][16 * tau + 4 * quad] = h4;
            }
            lacc[qg] *= al;
#pragma unroll
            for (int dt = 0; dt < 4; ++dt) ot[dt][qg] *= al;
        }
        // ---- P B-frags from LDS (hi only) ----
        f16x8 pbh[2];
#pragma unroll
        for (int qg = 0; qg < 2; ++qg)
            pbh[qg] = *(const f16x8*)&Phi[16 * qg + c16][quad * 8];
        // ---- PV (single term) + l via ones-row ----
#pragma unroll
        for (int dt = 0; dt < 4; ++dt)
#pragma unroll
            for (int qg = 0; qg < 2; ++qg)
                ot[dt][qg] = MFMA32(zh[dt], pbh[qg], ot[dt][qg]);
#pragma unroll
        for (int qg = 0; qg < 2; ++qg)
            lacc[qg] = MFMA32(ones, pbh[qg], lacc[qg]);
        // ---- S_{t+1} ----
        if (more) doS(kh2, kl2);
    };

    loadK(tile0, kAh, kAl);
    doS(kAh, kAl);
#pragma unroll 1
    for (int tt = 0; tt < ITERS; tt += 2) {
        body(tt,     kBh, kBl);
        body(tt + 1, kAh, kAl);
    }

    // epilogue: unnormalized O + m (log2 domain), l partials
    const size_t obase = (size_t)(side * KS + blockIdx.z) * N;
#pragma unroll
    for (int qg = 0; qg < 2; ++qg) {
        int q = q0 + 16 * qg + c16;
#pragma unroll
        for (int dt = 0; dt < 4; ++dt)
            *(f32x4*)&Opart[(obase + q) * D + 16 * dt + 4 * quad] = ot[dt][qg];
        if (quad == 0) {
            mpart[obase + q] = m_run[qg];
            lpart[obase + q] = lacc[qg][0];
        }
    }
}

// ---------------------------------------------------------------------------
// K4: combine split-K partials -> Xf/Yf (frag-major f16 hi/lo; x side scaled
// by 2*log2e for exp2-domain RBF) + row norms scaled by log2e.
// ---------------------------------------------------------------------------
template<int KS>
__global__ __launch_bounds__(256) void combine_kernel(
    const float* __restrict__ Opart, const float* __restrict__ mpart,
    const float* __restrict__ lpart,
    half_t* __restrict__ Xf, half_t* __restrict__ Yf,
    float* __restrict__ n2x, float* __restrict__ n2y)
{
    const int side = blockIdx.y;
    const int q = blockIdx.x * 16 + (threadIdx.x >> 4);
    const int d4 = (threadIdx.x & 15) * 4;
    float m[KS], l[KS];
#pragma unroll
    for (int s = 0; s < KS; ++s) {
        size_t b = (size_t)(side * KS + s) * N + q;
        m[s] = mpart[b]; l[s] = lpart[b];
    }
    float M = -INFINITY;
#pragma unroll
    for (int s = 0; s < KS; ++s) M = fmaxf(M, m[s]);
    float L = 0.f;
    f32x4 o = {0.f, 0.f, 0.f, 0.f};
#pragma unroll
    for (int s = 0; s < KS; ++s) {
        float sc = exp2f(m[s] - M);
        L += l[s] * sc;
        f32x4 p = *(const f32x4*)&Opart[((size_t)(side * KS + s) * N + q) * D + d4];
        o += p * sc;
    }
    float inv = 1.f / L;
    o *= inv;
    float sq = o[0] * o[0] + o[1] * o[1] + o[2] * o[2] + o[3] * o[3];
#pragma unroll
    for (int off = 1; off < 16; off <<= 1) sq += __shfl_xor(sq, off);
    half_t* dst = side ? Yf : Xf;
    float*  n2  = side ? n2y : n2x;
    if ((threadIdx.x & 15) == 0) n2[q] = sq * LOG2E;
    const float oscale = side ? 1.0f : 2.0f * LOG2E;   // exp2-domain dot on x side
    f16x4 h4, l4;
#pragma unroll
    for (int i = 0; i < 4; ++i) { float v = o[i] * oscale; SPLIT(v, h4[i], l4[i]); }
    const int tile16 = q >> 4, c16l = q & 15;
    const int ksi = d4 >> 5, quadi = (d4 >> 3) & 3, j0 = d4 & 7;
    size_t idx = (size_t)tile16 * 2048 + ksi * 1024 + (quadi * 16 + c16l) * 8 + j0;
    *(f16x4*)&dst[idx]       = h4;
    *(f16x4*)&dst[idx + 512] = l4;
}

// ---------------------------------------------------------------------------
// K5: RBF via MFMA, frag-major coalesced loads, 3-term hi/lo (abs precision
// on the dot matters). Block = 4 waves (2x2), 128x128 tile, 64x64/wave.
// ---------------------------------------------------------------------------
__global__ __launch_bounds__(256, 3) void rbf_kernel(
    const half_t* __restrict__ Xf, const half_t* __restrict__ Yf,
    const float* __restrict__ n2x, const float* __restrict__ n2y,
    float* __restrict__ out)
{
    const int t = threadIdx.x, w = t >> 6, lane = t & 63;
    const int c16 = lane & 15, quad = lane >> 4;
    const int X0 = blockIdx.y * 128 + (w >> 1) * 64;
    const int Y0 = blockIdx.x * 128 + (w & 1) * 64;
    float ny[4];
    f32x4 nx4[4];
#pragma unroll
    for (int yt = 0; yt < 4; ++yt) ny[yt] = n2y[Y0 + 16 * yt + c16];
#pragma unroll
    for (int xt = 0; xt < 4; ++xt)
        nx4[xt] = *(const f32x4*)&n2x[X0 + 16 * xt + 4 * quad];

    const half_t* Xb = Xf + lane * 8;
    const half_t* Yb = Yf + lane * 8;
    f32x4 acc[4][4] = {};   // [xt][yt]
#pragma unroll
    for (int ks = 0; ks < 2; ++ks) {
        f16x8 bh[4], bl[4];
#pragma unroll
        for (int yt = 0; yt < 4; ++yt) {
            size_t off = (size_t)((Y0 >> 4) + yt) * 2048 + ks * 1024;
            bh[yt] = *(const f16x8*)&Yb[off];
            bl[yt] = *(const f16x8*)&Yb[off + 512];
        }
#pragma unroll
        for (int xt = 0; xt < 4; ++xt) {
            size_t ao = (size_t)((X0 >> 4) + xt) * 2048 + ks * 1024;
            f16x8 ah = *(const f16x8*)&Xb[ao];
            f16x8 al = *(const f16x8*)&Xb[ao + 512];
#pragma unroll
            for (int yt = 0; yt < 4; ++yt) {
                acc[xt][yt] = MFMA32(ah, bh[yt], acc[xt][yt]);
                acc[xt][yt] = MFMA32(ah, bl[yt], acc[xt][yt]);
                acc[xt][yt] = MFMA32(al, bh[yt], acc[xt][yt]);
            }
        }
    }
#pragma unroll
    for (int xt = 0; xt < 4; ++xt)
#pragma unroll
        for (int r = 0; r < 4; ++r) {
            int xr = X0 + 16 * xt + 4 * quad + r;
            float nx = nx4[xt][r];
#pragma unroll
            for (int yt = 0; yt < 4; ++yt) {
                float v = exp2f(acc[xt][yt][r] - nx - ny[yt]);
                out[(size_t)xr * N + Y0 + 16 * yt + c16] = v;
            }
        }
}

// ---------------------------------------------------------------------------
extern "C" void kernel_launch(void* const* d_in, const int* in_sizes, int n_in,
                              void* d_out, int out_size, void* d_ws, size_t ws_size,
                              hipStream_t stream) {
    const float* Wq = (const float*)d_in[0];
    const float* Wk = (const float*)d_in[1];
    const float* x  = (const float*)d_in[2];
    const float* y  = (const float*)d_in[3];
    float* out = (float*)d_out;

    char* p = (char*)d_ws;
    size_t used = 0;
    auto alloc = [&](size_t bytes) -> void* {
        void* r = (void*)(p + used);
        used += (bytes + 255) & ~(size_t)255;
        return r;
    };
    float*  Qx  = (float*) alloc((size_t)N * D * 4);
    float*  Qy  = (float*) alloc((size_t)N * D * 4);
    half_t* Kfx = (half_t*)alloc((size_t)N * D * 2 * 2);   // hi+lo
    half_t* Kfy = (half_t*)alloc((size_t)N * D * 2 * 2);
    half_t* Zfx = (half_t*)alloc((size_t)N * D * 2);       // hi only
    half_t* Zfy = (half_t*)alloc((size_t)N * D * 2);
    half_t* Xf  = (half_t*)alloc((size_t)N * D * 2 * 2);
    half_t* Yf  = (half_t*)alloc((size_t)N * D * 2 * 2);
    float*  n2x = (float*) alloc((size_t)N * 4);
    float*  n2y = (float*) alloc((size_t)N * 4);

    const size_t base = used;
    const size_t per_split = (size_t)2 * N * D * 4 + (size_t)2 * N * 4 * 2 + 3 * 256;
    int KS = 4;
    if      (ws_size >= base + 16 * per_split) KS = 16;
    else if (ws_size >= base +  8 * per_split) KS = 8;

    float* Opart = (float*)alloc((size_t)2 * KS * N * D * 4);
    float* mpart = (float*)alloc((size_t)2 * KS * N * 4);
    float* lpart = (float*)alloc((size_t)2 * KS * N * 4);

    proj_kernel<<<dim3(2 * N / 16), 256, 0, stream>>>(Wq, Wk, x, y, Qx, Qy, Kfx, Kfy);
    ztprep_kernel<<<dim3(N / 32, 2), 256, 0, stream>>>(x, y, Zfx, Zfy);
    if (KS == 16) {
        attn_kernel<16><<<dim3(N / 128, 2, 16), 256, 0, stream>>>(
            Qx, Qy, Kfx, Kfy, Zfx, Zfy, Opart, mpart, lpart);
        combine_kernel<16><<<dim3(N / 16, 2), 256, 0, stream>>>(
            Opart, mpart, lpart, Xf, Yf, n2x, n2y);
    } else if (KS == 8) {
        attn_kernel<8><<<dim3(N / 128, 2, 8), 256, 0, stream>>>(
            Qx, Qy, Kfx, Kfy, Zfx, Zfy, Opart, mpart, lpart);
        combine_kernel<8><<<dim3(N / 16, 2), 256, 0, stream>>>(
            Opart, mpart, lpart, Xf, Yf, n2x, n2y);
    } else {
        attn_kernel<4><<<dim3(N / 128, 2, 4), 256, 0, stream>>>(
            Qx, Qy, Kfx, Kfy, Zfx, Zfy, Opart, mpart, lpart);
        combine_kernel<4><<<dim3(N / 16, 2), 256, 0, stream>>>(
            Opart, mpart, lpart, Xf, Yf, n2x, n2y);
    }
    rbf_kernel<<<dim3(N / 128, N / 128), 256, 0, stream>>>(Xf, Yf, n2x, n2y, out);
}

// Round 7
// 392.572 us; speedup vs baseline: 1.9195x; 1.0922x over previous
//
#include <hip/hip_runtime.h>
#include <math.h>

#define N 8192
#define D 64
#define LOG2E 1.4426950408889634f

typedef _Float16 half_t;
typedef _Float16 f16x8 __attribute__((ext_vector_type(8)));
typedef _Float16 f16x4 __attribute__((ext_vector_type(4)));
typedef float f32x4 __attribute__((ext_vector_type(4)));

#define MFMA32(a, b, c) __builtin_amdgcn_mfma_f32_16x16x32_f16((a), (b), (c), 0, 0, 0)

// split a f32 into f16 hi + f16 lo (v ~= hi + lo, rel err ~2^-22)
#define SPLIT(v, H, L) { half_t _h = (half_t)(v); (H) = _h; (L) = (half_t)((v) - (float)_h); }

// Fragment-major layouts (hot-loop loads are base + lane*16B):
//  Qf,Kf [tile32][ks][tau][hl][lane][8] : elem (row=tile*32+tau*16+c16, col=ks*32+quad*8+j)
//  Zf    [tile32][dt][lane][8]          : elem (row=tile*32+quad*8+j, d=dt*16+c16)  HI only
//  XYf   [tile16][ks][lane][8]          : elem (row=tile*16+c16, col=ks*32+quad*8+j) HI only
// where lane = quad*16 + c16.

// ---------------------------------------------------------------------------
// K1: Qf = (X@Wq)*0.125*log2e, Kf = X@Wk, both f16 hi/lo frag-major.
// ---------------------------------------------------------------------------
__global__ __launch_bounds__(256) void proj_kernel(
    const float* __restrict__ Wq, const float* __restrict__ Wk,
    const float* __restrict__ X, const float* __restrict__ Y,
    half_t* __restrict__ Qfx, half_t* __restrict__ Qfy,
    half_t* __restrict__ Kfx, half_t* __restrict__ Kfy)
{
    __shared__ float sWq[64][64];
    __shared__ float sWk[64][64];
    __shared__ float sIn[16][64];
    const int t = threadIdx.x;
#pragma unroll
    for (int p = 0; p < 16; ++p) {
        int idx = p * 256 + t;
        sWq[idx >> 6][idx & 63] = Wq[idx];
        sWk[idx >> 6][idx & 63] = Wk[idx];
    }
    const int R0 = blockIdx.x * 16;
    const float* src; half_t* dqf; half_t* dkf; int r0;
    if (R0 < N) { src = X; dqf = Qfx; dkf = Kfx; r0 = R0; }
    else        { src = Y; dqf = Qfy; dkf = Kfy; r0 = R0 - N; }
#pragma unroll
    for (int p = 0; p < 4; ++p) {
        int idx = p * 256 + t;
        sIn[idx >> 6][idx & 63] = src[(size_t)r0 * D + idx];
    }
    __syncthreads();
    const int c = t & 63;
    const int rb = t >> 6;
    const int ksi = c >> 5, quadi = (c >> 3) & 3, j = c & 7;
#pragma unroll
    for (int rr = 0; rr < 4; ++rr) {
        int r = rr * 4 + rb;
        float aq = 0.f, ak = 0.f;
#pragma unroll
        for (int k = 0; k < 64; ++k) {
            float xv = sIn[r][k];
            aq = fmaf(xv, sWq[k][c], aq);
            ak = fmaf(xv, sWk[k][c], ak);
        }
        aq *= (0.125f * LOG2E);
        int rg = r0 + r;
        int tile = rg >> 5, tau = (rg >> 4) & 1, c16l = rg & 15;
        size_t idx = (size_t)tile * 4096 + ksi * 2048 + tau * 1024
                   + (quadi * 16 + c16l) * 8 + j;
        half_t qhh = (half_t)aq;
        dqf[idx]       = qhh;
        dqf[idx + 512] = (half_t)(aq - (float)qhh);
        half_t khh = (half_t)ak;
        dkf[idx]       = khh;
        dkf[idx + 512] = (half_t)(ak - (float)khh);
    }
}

// ---------------------------------------------------------------------------
// K2: Zf prep (transposed input, f16 HI only, frag-major). grid (N/32, 2).
// ---------------------------------------------------------------------------
__global__ __launch_bounds__(256) void ztprep_kernel(
    const float* __restrict__ X, const float* __restrict__ Y,
    half_t* __restrict__ Zfx, half_t* __restrict__ Zfy)
{
    const int t = threadIdx.x;
    const int tile = blockIdx.x;
    const float* src = blockIdx.y ? Y : X;
    half_t* dst = blockIdx.y ? Zfy : Zfx;
    const int dt = t >> 6, lane = t & 63;
    const int quad = lane >> 4, c16 = lane & 15;
    f16x8 h;
#pragma unroll
    for (int j = 0; j < 8; ++j)
        h[j] = (half_t)src[(size_t)(tile * 32 + quad * 8 + j) * D + dt * 16 + c16];
    *(f16x8*)&dst[(size_t)tile * 2048 + dt * 512 + lane * 8] = h;
}

// ---------------------------------------------------------------------------
// K3: flash attention. S = 3-term f16 hi/lo (score noise flips near-tied
// argmaxes -> keep abs precision). P/Z hi-only (one-hot softmax cancels
// multiplicative noise). st DOUBLE-BUFFERED: S(t+1) issues FIRST in body(t)
// so its MFMAs overlap softmax(t)'s VALU + LDS round-trip. grid (N/128,2,KS).
// ---------------------------------------------------------------------------
template<int KS>
__global__ __launch_bounds__(256, 2) void attn_kernel(
    const half_t* __restrict__ Qfx, const half_t* __restrict__ Qfy,
    const half_t* __restrict__ Kfx, const half_t* __restrict__ Kfy,
    const half_t* __restrict__ Zfx, const half_t* __restrict__ Zfy,
    float* __restrict__ Opart, float* __restrict__ mpart, float* __restrict__ lpart)
{
    const int side = blockIdx.y;
    const half_t* Qf = side ? Qfy : Qfx;
    const half_t* Kf = side ? Kfy : Kfx;
    const half_t* Zf = side ? Zfy : Zfx;
    const int t = threadIdx.x, w = t >> 6, lane = t & 63;
    const int c16 = lane & 15, quad = lane >> 4;
    const int q0 = blockIdx.x * 128 + w * 32;
    const int tile0 = blockIdx.z * (N / KS / 32);
    const int ITERS = (N / KS) / 32;

    __shared__ half_t Pbuf[4][32][40];   // [wave][q][kv(+pad)] hi only
    half_t (*Phi)[40] = Pbuf[w];

    // Q fragments straight from frag-major global (B-operand: n=c16=q, k=quad*8+j)
    f16x8 qh[2][2], ql[2][2];   // [qg][ks]
    {
        const half_t* qb = Qf + (size_t)(q0 >> 5) * 4096 + lane * 8;
#pragma unroll
        for (int ks = 0; ks < 2; ++ks)
#pragma unroll
            for (int qg = 0; qg < 2; ++qg) {
                qh[qg][ks] = *(const f16x8*)&qb[ks * 2048 + qg * 1024];
                ql[qg][ks] = *(const f16x8*)&qb[ks * 2048 + qg * 1024 + 512];
            }
    }

    f32x4 ot[4][2] = {};      // O^T accumulators [dt][qg]
    f32x4 lacc[2] = {};       // l accumulators via ones-row MFMA
    float m_run[2] = {-INFINITY, -INFINITY};
    f16x8 ones;
#pragma unroll
    for (int i = 0; i < 8; ++i) ones[i] = (half_t)1.0f;

    f16x8 kAh[2][2], kAl[2][2], kBh[2][2], kBl[2][2];   // ping-pong K frags
    f32x4 stA[2][2], stB[2][2];                          // double-buffered S^T

    auto loadK = [&](int tile, f16x8 (&kh)[2][2], f16x8 (&kl)[2][2]) {
        const half_t* b = Kf + (size_t)tile * 4096 + lane * 8;
#pragma unroll
        for (int ks = 0; ks < 2; ++ks)
#pragma unroll
            for (int tau = 0; tau < 2; ++tau) {
                kh[ks][tau] = *(const f16x8*)&b[ks * 2048 + tau * 1024];
                kl[ks][tau] = *(const f16x8*)&b[ks * 2048 + tau * 1024 + 512];
            }
    };
    auto doS = [&](f32x4 (&st)[2][2], f16x8 (&kh)[2][2], f16x8 (&kl)[2][2]) {
        const f32x4 zero = {};
#pragma unroll
        for (int qg = 0; qg < 2; ++qg)
#pragma unroll
            for (int tau = 0; tau < 2; ++tau) st[qg][tau] = zero;
#pragma unroll
        for (int ks = 0; ks < 2; ++ks)
#pragma unroll
            for (int tau = 0; tau < 2; ++tau)
#pragma unroll
                for (int qg = 0; qg < 2; ++qg) {
                    st[qg][tau] = MFMA32(kh[ks][tau], qh[qg][ks], st[qg][tau]);
                    st[qg][tau] = MFMA32(kh[ks][tau], ql[qg][ks], st[qg][tau]);
                    st[qg][tau] = MFMA32(kl[ks][tau], qh[qg][ks], st[qg][tau]);
                }
    };

    // body(t): stCur holds S(t); kNew holds K(t+1) (in flight since body(t-1)).
    // 1) issue S(t+1) (MFMA background)  2) start K(t+2)/Z(t) loads
    // 3) softmax(t) on VALU (overlaps)   4) PV(t) + l
    auto body = [&](int tt, f32x4 (&stCur)[2][2], f32x4 (&stNext)[2][2],
                    f16x8 (&kNh)[2][2], f16x8 (&kNl)[2][2],
                    f16x8 (&kRh)[2][2], f16x8 (&kRl)[2][2]) {
        if (tt + 1 < ITERS) doS(stNext, kNh, kNl);          // S(t+1)
        if (tt + 2 < ITERS) loadK(tile0 + tt + 2, kRh, kRl); // K(t+2)
        const half_t* zb = Zf + (size_t)(tile0 + tt) * 2048 + lane * 8;
        f16x8 zh[4];
#pragma unroll
        for (int dt = 0; dt < 4; ++dt)
            zh[dt] = *(const f16x8*)&zb[dt * 512];
        // ---- online softmax (exp2 domain), P hi-only ----
#pragma unroll
        for (int qg = 0; qg < 2; ++qg) {
            float mt = fmaxf(fmaxf(fmaxf(stCur[qg][0][0], stCur[qg][0][1]),
                                   fmaxf(stCur[qg][0][2], stCur[qg][0][3])),
                             fmaxf(fmaxf(stCur[qg][1][0], stCur[qg][1][1]),
                                   fmaxf(stCur[qg][1][2], stCur[qg][1][3])));
            mt = fmaxf(mt, __shfl_xor(mt, 16));
            mt = fmaxf(mt, __shfl_xor(mt, 32));
            float mn = fmaxf(m_run[qg], mt);
            float al = exp2f(m_run[qg] - mn);
            m_run[qg] = mn;
#pragma unroll
            for (int tau = 0; tau < 2; ++tau) {
                f16x4 h4;
#pragma unroll
                for (int r = 0; r < 4; ++r)
                    h4[r] = (half_t)exp2f(stCur[qg][tau][r] - mn);
                *(f16x4*)&Phi[16 * qg + c16][16 * tau + 4 * quad] = h4;
            }
            lacc[qg] *= al;
#pragma unroll
            for (int dt = 0; dt < 4; ++dt) ot[dt][qg] *= al;
        }
        // ---- P B-frags from LDS, PV + l ----
        f16x8 pbh[2];
#pragma unroll
        for (int qg = 0; qg < 2; ++qg)
            pbh[qg] = *(const f16x8*)&Phi[16 * qg + c16][quad * 8];
#pragma unroll
        for (int dt = 0; dt < 4; ++dt)
#pragma unroll
            for (int qg = 0; qg < 2; ++qg)
                ot[dt][qg] = MFMA32(zh[dt], pbh[qg], ot[dt][qg]);
#pragma unroll
        for (int qg = 0; qg < 2; ++qg)
            lacc[qg] = MFMA32(ones, pbh[qg], lacc[qg]);
    };

    loadK(tile0, kAh, kAl);
    doS(stA, kAh, kAl);                         // S(0)
    if (ITERS > 1) loadK(tile0 + 1, kBh, kBl);  // K(1)
#pragma unroll 1
    for (int tt = 0; tt < ITERS; tt += 2) {
        body(tt,     stA, stB, kBh, kBl, kAh, kAl);
        body(tt + 1, stB, stA, kAh, kAl, kBh, kBl);
    }

    // epilogue: unnormalized O + m (log2 domain), l partials
    const size_t obase = (size_t)(side * KS + blockIdx.z) * N;
#pragma unroll
    for (int qg = 0; qg < 2; ++qg) {
        int q = q0 + 16 * qg + c16;
#pragma unroll
        for (int dt = 0; dt < 4; ++dt)
            *(f32x4*)&Opart[(obase + q) * D + 16 * dt + 4 * quad] = ot[dt][qg];
        if (quad == 0) {
            mpart[obase + q] = m_run[qg];
            lpart[obase + q] = lacc[qg][0];
        }
    }
}

// ---------------------------------------------------------------------------
// K4: combine split-K partials -> Xf/Yf f16 HI-only frag-major. Norms are
// computed FROM the f16-rounded values (consistent points => rounding moves
// the point, errors cancel in 2dot - nx - ny). x side pre-scaled by 2*log2e.
// ---------------------------------------------------------------------------
template<int KS>
__global__ __launch_bounds__(256) void combine_kernel(
    const float* __restrict__ Opart, const float* __restrict__ mpart,
    const float* __restrict__ lpart,
    half_t* __restrict__ Xf, half_t* __restrict__ Yf,
    float* __restrict__ n2x, float* __restrict__ n2y)
{
    const int side = blockIdx.y;
    const int q = blockIdx.x * 16 + (threadIdx.x >> 4);
    const int d4 = (threadIdx.x & 15) * 4;
    float m[KS], l[KS];
#pragma unroll
    for (int s = 0; s < KS; ++s) {
        size_t b = (size_t)(side * KS + s) * N + q;
        m[s] = mpart[b]; l[s] = lpart[b];
    }
    float M = -INFINITY;
#pragma unroll
    for (int s = 0; s < KS; ++s) M = fmaxf(M, m[s]);
    float L = 0.f;
    f32x4 o = {0.f, 0.f, 0.f, 0.f};
#pragma unroll
    for (int s = 0; s < KS; ++s) {
        float sc = exp2f(m[s] - M);
        L += l[s] * sc;
        f32x4 p = *(const f32x4*)&Opart[((size_t)(side * KS + s) * N + q) * D + d4];
        o += p * sc;
    }
    const float oscale = (side ? 1.0f : 2.0f * LOG2E) / L;
    f16x4 h4;
#pragma unroll
    for (int i = 0; i < 4; ++i) h4[i] = (half_t)(o[i] * oscale);
    // norms from the ROUNDED values:
    //   y: n2 = log2e * sum(yh^2) ;  x: n2 = sum(xh^2) / (4*log2e)
    float sq = 0.f;
#pragma unroll
    for (int i = 0; i < 4; ++i) { float hv = (float)h4[i]; sq = fmaf(hv, hv, sq); }
#pragma unroll
    for (int off = 1; off < 16; off <<= 1) sq += __shfl_xor(sq, off);
    half_t* dst = side ? Yf : Xf;
    float*  n2  = side ? n2y : n2x;
    if ((threadIdx.x & 15) == 0)
        n2[q] = side ? sq * LOG2E : sq * (0.25f / LOG2E);
    const int tile16 = q >> 4, c16l = q & 15;
    const int ksi = d4 >> 5, quadi = (d4 >> 3) & 3, j0 = d4 & 7;
    *(f16x4*)&dst[(size_t)tile16 * 1024 + ksi * 512 + (quadi * 16 + c16l) * 8 + j0] = h4;
}

// ---------------------------------------------------------------------------
// K5: RBF via single-term f16 MFMA (consistent-points numerics), frag-major
// loads. Block = 4 waves (2x2), 128x128 tile, 64x64/wave, 32 MFMAs/wave.
// ---------------------------------------------------------------------------
__global__ __launch_bounds__(256, 4) void rbf_kernel(
    const half_t* __restrict__ Xf, const half_t* __restrict__ Yf,
    const float* __restrict__ n2x, const float* __restrict__ n2y,
    float* __restrict__ out)
{
    const int t = threadIdx.x, w = t >> 6, lane = t & 63;
    const int c16 = lane & 15, quad = lane >> 4;
    const int X0 = blockIdx.y * 128 + (w >> 1) * 64;
    const int Y0 = blockIdx.x * 128 + (w & 1) * 64;
    float ny[4];
    f32x4 nx4[4];
#pragma unroll
    for (int yt = 0; yt < 4; ++yt) ny[yt] = n2y[Y0 + 16 * yt + c16];
#pragma unroll
    for (int xt = 0; xt < 4; ++xt)
        nx4[xt] = *(const f32x4*)&n2x[X0 + 16 * xt + 4 * quad];

    const half_t* Xb = Xf + lane * 8;
    const half_t* Yb = Yf + lane * 8;
    f32x4 acc[4][4] = {};   // [xt][yt]
#pragma unroll
    for (int ks = 0; ks < 2; ++ks) {
        f16x8 bh[4];
#pragma unroll
        for (int yt = 0; yt < 4; ++yt)
            bh[yt] = *(const f16x8*)&Yb[(size_t)((Y0 >> 4) + yt) * 1024 + ks * 512];
#pragma unroll
        for (int xt = 0; xt < 4; ++xt) {
            f16x8 ah = *(const f16x8*)&Xb[(size_t)((X0 >> 4) + xt) * 1024 + ks * 512];
#pragma unroll
            for (int yt = 0; yt < 4; ++yt)
                acc[xt][yt] = MFMA32(ah, bh[yt], acc[xt][yt]);
        }
    }
#pragma unroll
    for (int xt = 0; xt < 4; ++xt)
#pragma unroll
        for (int r = 0; r < 4; ++r) {
            int xr = X0 + 16 * xt + 4 * quad + r;
            float nx = nx4[xt][r];
#pragma unroll
            for (int yt = 0; yt < 4; ++yt) {
                float v = exp2f(acc[xt][yt][r] - nx - ny[yt]);
                out[(size_t)xr * N + Y0 + 16 * yt + c16] = v;
            }
        }
}

// ---------------------------------------------------------------------------
extern "C" void kernel_launch(void* const* d_in, const int* in_sizes, int n_in,
                              void* d_out, int out_size, void* d_ws, size_t ws_size,
                              hipStream_t stream) {
    const float* Wq = (const float*)d_in[0];
    const float* Wk = (const float*)d_in[1];
    const float* x  = (const float*)d_in[2];
    const float* y  = (const float*)d_in[3];
    float* out = (float*)d_out;

    char* p = (char*)d_ws;
    size_t used = 0;
    auto alloc = [&](size_t bytes) -> void* {
        void* r = (void*)(p + used);
        used += (bytes + 255) & ~(size_t)255;
        return r;
    };
    half_t* Qfx = (half_t*)alloc((size_t)N * D * 2 * 2);   // hi+lo frag-major
    half_t* Qfy = (half_t*)alloc((size_t)N * D * 2 * 2);
    half_t* Kfx = (half_t*)alloc((size_t)N * D * 2 * 2);
    half_t* Kfy = (half_t*)alloc((size_t)N * D * 2 * 2);
    half_t* Zfx = (half_t*)alloc((size_t)N * D * 2);       // hi only
    half_t* Zfy = (half_t*)alloc((size_t)N * D * 2);
    half_t* Xf  = (half_t*)alloc((size_t)N * D * 2);       // hi only
    half_t* Yf  = (half_t*)alloc((size_t)N * D * 2);
    float*  n2x = (float*) alloc((size_t)N * 4);
    float*  n2y = (float*) alloc((size_t)N * 4);

    const size_t base = used;
    const size_t per_split = (size_t)2 * N * D * 4 + (size_t)2 * N * 4 * 2 + 3 * 256;
    int KS = 4;
    if      (ws_size >= base + 16 * per_split) KS = 16;
    else if (ws_size >= base +  8 * per_split) KS = 8;

    float* Opart = (float*)alloc((size_t)2 * KS * N * D * 4);
    float* mpart = (float*)alloc((size_t)2 * KS * N * 4);
    float* lpart = (float*)alloc((size_t)2 * KS * N * 4);

    proj_kernel<<<dim3(2 * N / 16), 256, 0, stream>>>(Wq, Wk, x, y,
                                                      Qfx, Qfy, Kfx, Kfy);
    ztprep_kernel<<<dim3(N / 32, 2), 256, 0, stream>>>(x, y, Zfx, Zfy);
    if (KS == 16) {
        attn_kernel<16><<<dim3(N / 128, 2, 16), 256, 0, stream>>>(
            Qfx, Qfy, Kfx, Kfy, Zfx, Zfy, Opart, mpart, lpart);
        combine_kernel<16><<<dim3(N / 16, 2), 256, 0, stream>>>(
            Opart, mpart, lpart, Xf, Yf, n2x, n2y);
    } else if (KS == 8) {
        attn_kernel<8><<<dim3(N / 128, 2, 8), 256, 0, stream>>>(
            Qfx, Qfy, Kfx, Kfy, Zfx, Zfy, Opart, mpart, lpart);
        combine_kernel<8><<<dim3(N / 16, 2), 256, 0, stream>>>(
            Opart, mpart, lpart, Xf, Yf, n2x, n2y);
    } else {
        attn_kernel<4><<<dim3(N / 128, 2, 4), 256, 0, stream>>>(
            Qfx, Qfy, Kfx, Kfy, Zfx, Zfy, Opart, mpart, lpart);
        combine_kernel<4><<<dim3(N / 16, 2), 256, 0, stream>>>(
            Opart, mpart, lpart, Xf, Yf, n2x, n2y);
    }
    rbf_kernel<<<dim3(N / 128, N / 128), 256, 0, stream>>>(Xf, Yf, n2x, n2y, out);
}

// Round 8
// 391.910 us; speedup vs baseline: 1.9228x; 1.0017x over previous
//
#include <hip/hip_runtime.h>
#include <math.h>

#define N 8192
#define D 64
#define KS 4
#define LOG2E 1.4426950408889634f

typedef _Float16 half_t;
typedef _Float16 f16x8 __attribute__((ext_vector_type(8)));
typedef _Float16 f16x4 __attribute__((ext_vector_type(4)));
typedef float f32x4 __attribute__((ext_vector_type(4)));

#define MFMA32(a, b, c) __builtin_amdgcn_mfma_f32_16x16x32_f16((a), (b), (c), 0, 0, 0)

// split a f32 into f16 hi + f16 lo (v ~= hi + lo, rel err ~2^-22)
#define SPLIT(v, H, L) { half_t _h = (half_t)(v); (H) = _h; (L) = (half_t)((v) - (float)_h); }

// Fragment-major layouts (hot-loop loads are base + lane*16B):
//  Qf,Kf [tile32][ks][tau][hl][lane][8] : elem (row=tile*32+tau*16+c16, col=ks*32+quad*8+j)
//  Zf    [tile32][dt][lane][8]          : elem (row=tile*32+quad*8+j, d=dt*16+c16)  HI only
//  XYf   [tile16][ks][lane][8]          : elem (row=tile*16+c16, col=ks*32+quad*8+j) HI only
// where lane = quad*16 + c16.

// ---------------------------------------------------------------------------
// K1: Qf = (X@Wq)*0.125*log2e, Kf = X@Wk, both f16 hi/lo frag-major.
// ---------------------------------------------------------------------------
__global__ __launch_bounds__(256) void proj_kernel(
    const float* __restrict__ Wq, const float* __restrict__ Wk,
    const float* __restrict__ X, const float* __restrict__ Y,
    half_t* __restrict__ Qfx, half_t* __restrict__ Qfy,
    half_t* __restrict__ Kfx, half_t* __restrict__ Kfy)
{
    __shared__ float sWq[64][64];
    __shared__ float sWk[64][64];
    __shared__ float sIn[16][64];
    const int t = threadIdx.x;
#pragma unroll
    for (int p = 0; p < 16; ++p) {
        int idx = p * 256 + t;
        sWq[idx >> 6][idx & 63] = Wq[idx];
        sWk[idx >> 6][idx & 63] = Wk[idx];
    }
    const int R0 = blockIdx.x * 16;
    const float* src; half_t* dqf; half_t* dkf; int r0;
    if (R0 < N) { src = X; dqf = Qfx; dkf = Kfx; r0 = R0; }
    else        { src = Y; dqf = Qfy; dkf = Kfy; r0 = R0 - N; }
#pragma unroll
    for (int p = 0; p < 4; ++p) {
        int idx = p * 256 + t;
        sIn[idx >> 6][idx & 63] = src[(size_t)r0 * D + idx];
    }
    __syncthreads();
    const int c = t & 63;
    const int rb = t >> 6;
    const int ksi = c >> 5, quadi = (c >> 3) & 3, j = c & 7;
#pragma unroll
    for (int rr = 0; rr < 4; ++rr) {
        int r = rr * 4 + rb;
        float aq = 0.f, ak = 0.f;
#pragma unroll
        for (int k = 0; k < 64; ++k) {
            float xv = sIn[r][k];
            aq = fmaf(xv, sWq[k][c], aq);
            ak = fmaf(xv, sWk[k][c], ak);
        }
        aq *= (0.125f * LOG2E);
        int rg = r0 + r;
        int tile = rg >> 5, tau = (rg >> 4) & 1, c16l = rg & 15;
        size_t idx = (size_t)tile * 4096 + ksi * 2048 + tau * 1024
                   + (quadi * 16 + c16l) * 8 + j;
        half_t qhh = (half_t)aq;
        dqf[idx]       = qhh;
        dqf[idx + 512] = (half_t)(aq - (float)qhh);
        half_t khh = (half_t)ak;
        dkf[idx]       = khh;
        dkf[idx + 512] = (half_t)(ak - (float)khh);
    }
}

// ---------------------------------------------------------------------------
// K2: Zf prep (transposed input, f16 HI only, frag-major). grid (N/32, 2).
// ---------------------------------------------------------------------------
__global__ __launch_bounds__(256) void ztprep_kernel(
    const float* __restrict__ X, const float* __restrict__ Y,
    half_t* __restrict__ Zfx, half_t* __restrict__ Zfy)
{
    const int t = threadIdx.x;
    const int tile = blockIdx.x;
    const float* src = blockIdx.y ? Y : X;
    half_t* dst = blockIdx.y ? Zfy : Zfx;
    const int dt = t >> 6, lane = t & 63;
    const int quad = lane >> 4, c16 = lane & 15;
    f16x8 h;
#pragma unroll
    for (int j = 0; j < 8; ++j)
        h[j] = (half_t)src[(size_t)(tile * 32 + quad * 8 + j) * D + dt * 16 + c16];
    *(f16x8*)&dst[(size_t)tile * 2048 + dt * 512 + lane * 8] = h;
}

// ---------------------------------------------------------------------------
// K3: flash attention. S = 3-term f16 hi/lo (score noise flips near-tied
// argmaxes -> keep abs precision). P/Z hi-only. st double-buffered: S(t+1)
// MFMAs issue first in body(t), overlapping softmax(t) VALU + LDS round-trip.
// KS=4 -> grid 512 = exactly 2 blocks/CU (matches launch_bounds(256,2)).
// Partials stored f16 (dominant-split rel noise == final f16 rounding scale).
// ---------------------------------------------------------------------------
__global__ __launch_bounds__(256, 2) void attn_kernel(
    const half_t* __restrict__ Qfx, const half_t* __restrict__ Qfy,
    const half_t* __restrict__ Kfx, const half_t* __restrict__ Kfy,
    const half_t* __restrict__ Zfx, const half_t* __restrict__ Zfy,
    half_t* __restrict__ Opart, float* __restrict__ mpart, float* __restrict__ lpart)
{
    const int side = blockIdx.y;
    const half_t* Qf = side ? Qfy : Qfx;
    const half_t* Kf = side ? Kfy : Kfx;
    const half_t* Zf = side ? Zfy : Zfx;
    const int t = threadIdx.x, w = t >> 6, lane = t & 63;
    const int c16 = lane & 15, quad = lane >> 4;
    const int q0 = blockIdx.x * 128 + w * 32;
    const int tile0 = blockIdx.z * (N / KS / 32);
    const int ITERS = (N / KS) / 32;   // 64

    __shared__ half_t Pbuf[4][32][40];   // [wave][q][kv(+pad)] hi only
    half_t (*Phi)[40] = Pbuf[w];

    // Q fragments straight from frag-major global (B-operand: n=c16=q, k=quad*8+j)
    f16x8 qh[2][2], ql[2][2];   // [qg][ks]
    {
        const half_t* qb = Qf + (size_t)(q0 >> 5) * 4096 + lane * 8;
#pragma unroll
        for (int ks = 0; ks < 2; ++ks)
#pragma unroll
            for (int qg = 0; qg < 2; ++qg) {
                qh[qg][ks] = *(const f16x8*)&qb[ks * 2048 + qg * 1024];
                ql[qg][ks] = *(const f16x8*)&qb[ks * 2048 + qg * 1024 + 512];
            }
    }

    f32x4 ot[4][2] = {};      // O^T accumulators [dt][qg]
    f32x4 lacc[2] = {};       // l accumulators via ones-row MFMA
    float m_run[2] = {-INFINITY, -INFINITY};
    f16x8 ones;
#pragma unroll
    for (int i = 0; i < 8; ++i) ones[i] = (half_t)1.0f;

    f16x8 kAh[2][2], kAl[2][2], kBh[2][2], kBl[2][2];   // ping-pong K frags
    f32x4 stA[2][2], stB[2][2];                          // double-buffered S^T

    auto loadK = [&](int tile, f16x8 (&kh)[2][2], f16x8 (&kl)[2][2]) {
        const half_t* b = Kf + (size_t)tile * 4096 + lane * 8;
#pragma unroll
        for (int ks = 0; ks < 2; ++ks)
#pragma unroll
            for (int tau = 0; tau < 2; ++tau) {
                kh[ks][tau] = *(const f16x8*)&b[ks * 2048 + tau * 1024];
                kl[ks][tau] = *(const f16x8*)&b[ks * 2048 + tau * 1024 + 512];
            }
    };
    auto doS = [&](f32x4 (&st)[2][2], f16x8 (&kh)[2][2], f16x8 (&kl)[2][2]) {
        const f32x4 zero = {};
#pragma unroll
        for (int qg = 0; qg < 2; ++qg)
#pragma unroll
            for (int tau = 0; tau < 2; ++tau) st[qg][tau] = zero;
#pragma unroll
        for (int ks = 0; ks < 2; ++ks)
#pragma unroll
            for (int tau = 0; tau < 2; ++tau)
#pragma unroll
                for (int qg = 0; qg < 2; ++qg) {
                    st[qg][tau] = MFMA32(kh[ks][tau], qh[qg][ks], st[qg][tau]);
                    st[qg][tau] = MFMA32(kh[ks][tau], ql[qg][ks], st[qg][tau]);
                    st[qg][tau] = MFMA32(kl[ks][tau], qh[qg][ks], st[qg][tau]);
                }
    };

    auto body = [&](int tt, f32x4 (&stCur)[2][2], f32x4 (&stNext)[2][2],
                    f16x8 (&kNh)[2][2], f16x8 (&kNl)[2][2],
                    f16x8 (&kRh)[2][2], f16x8 (&kRl)[2][2]) {
        if (tt + 1 < ITERS) doS(stNext, kNh, kNl);           // S(t+1) in background
        if (tt + 2 < ITERS) loadK(tile0 + tt + 2, kRh, kRl); // K(t+2) in flight
        const half_t* zb = Zf + (size_t)(tile0 + tt) * 2048 + lane * 8;
        f16x8 zh[4];
#pragma unroll
        for (int dt = 0; dt < 4; ++dt)
            zh[dt] = *(const f16x8*)&zb[dt * 512];
        // ---- online softmax (exp2 domain), P hi-only ----
#pragma unroll
        for (int qg = 0; qg < 2; ++qg) {
            float mt = fmaxf(fmaxf(fmaxf(stCur[qg][0][0], stCur[qg][0][1]),
                                   fmaxf(stCur[qg][0][2], stCur[qg][0][3])),
                             fmaxf(fmaxf(stCur[qg][1][0], stCur[qg][1][1]),
                                   fmaxf(stCur[qg][1][2], stCur[qg][1][3])));
            mt = fmaxf(mt, __shfl_xor(mt, 16));
            mt = fmaxf(mt, __shfl_xor(mt, 32));
            float mn = fmaxf(m_run[qg], mt);
            float al = exp2f(m_run[qg] - mn);
            m_run[qg] = mn;
#pragma unroll
            for (int tau = 0; tau < 2; ++tau) {
                f16x4 h4;
#pragma unroll
                for (int r = 0; r < 4; ++r)
                    h4[r] = (half_t)exp2f(stCur[qg][tau][r] - mn);
                *(f16x4*)&Phi[16 * qg + c16][16 * tau + 4 * quad] = h4;
            }
            lacc[qg] *= al;
#pragma unroll
            for (int dt = 0; dt < 4; ++dt) ot[dt][qg] *= al;
        }
        // ---- P B-frags from LDS, PV + l ----
        f16x8 pbh[2];
#pragma unroll
        for (int qg = 0; qg < 2; ++qg)
            pbh[qg] = *(const f16x8*)&Phi[16 * qg + c16][quad * 8];
#pragma unroll
        for (int dt = 0; dt < 4; ++dt)
#pragma unroll
            for (int qg = 0; qg < 2; ++qg)
                ot[dt][qg] = MFMA32(zh[dt], pbh[qg], ot[dt][qg]);
#pragma unroll
        for (int qg = 0; qg < 2; ++qg)
            lacc[qg] = MFMA32(ones, pbh[qg], lacc[qg]);
    };

    loadK(tile0, kAh, kAl);
    doS(stA, kAh, kAl);                         // S(0)
    if (ITERS > 1) loadK(tile0 + 1, kBh, kBl);  // K(1)
#pragma unroll 1
    for (int tt = 0; tt < ITERS; tt += 2) {
        body(tt,     stA, stB, kBh, kBl, kAh, kAl);
        body(tt + 1, stB, stA, kAh, kAl, kBh, kBl);
    }

    // epilogue: unnormalized O (f16, relative to m_run) + m, l partials (f32)
    const size_t obase = (size_t)(side * KS + blockIdx.z) * N;
#pragma unroll
    for (int qg = 0; qg < 2; ++qg) {
        int q = q0 + 16 * qg + c16;
#pragma unroll
        for (int dt = 0; dt < 4; ++dt) {
            f16x4 o4;
#pragma unroll
            for (int r = 0; r < 4; ++r) o4[r] = (half_t)ot[dt][qg][r];
            *(f16x4*)&Opart[(obase + q) * D + 16 * dt + 4 * quad] = o4;
        }
        if (quad == 0) {
            mpart[obase + q] = m_run[qg];
            lpart[obase + q] = lacc[qg][0];
        }
    }
}

// ---------------------------------------------------------------------------
// K4: combine split-K partials (f16) -> Xf/Yf f16 HI-only frag-major. Norms
// computed FROM the rounded values (consistent points). x side scaled 2*log2e.
// ---------------------------------------------------------------------------
__global__ __launch_bounds__(256) void combine_kernel(
    const half_t* __restrict__ Opart, const float* __restrict__ mpart,
    const float* __restrict__ lpart,
    half_t* __restrict__ Xf, half_t* __restrict__ Yf,
    float* __restrict__ n2x, float* __restrict__ n2y)
{
    const int side = blockIdx.y;
    const int q = blockIdx.x * 16 + (threadIdx.x >> 4);
    const int d4 = (threadIdx.x & 15) * 4;
    float m[KS], l[KS];
#pragma unroll
    for (int s = 0; s < KS; ++s) {
        size_t b = (size_t)(side * KS + s) * N + q;
        m[s] = mpart[b]; l[s] = lpart[b];
    }
    float M = -INFINITY;
#pragma unroll
    for (int s = 0; s < KS; ++s) M = fmaxf(M, m[s]);
    float L = 0.f;
    f32x4 o = {0.f, 0.f, 0.f, 0.f};
#pragma unroll
    for (int s = 0; s < KS; ++s) {
        float sc = exp2f(m[s] - M);
        L += l[s] * sc;
        f16x4 p4 = *(const f16x4*)&Opart[((size_t)(side * KS + s) * N + q) * D + d4];
#pragma unroll
        for (int i = 0; i < 4; ++i) o[i] = fmaf((float)p4[i], sc, o[i]);
    }
    const float oscale = (side ? 1.0f : 2.0f * LOG2E) / L;
    f16x4 h4;
#pragma unroll
    for (int i = 0; i < 4; ++i) h4[i] = (half_t)(o[i] * oscale);
    float sq = 0.f;
#pragma unroll
    for (int i = 0; i < 4; ++i) { float hv = (float)h4[i]; sq = fmaf(hv, hv, sq); }
#pragma unroll
    for (int off = 1; off < 16; off <<= 1) sq += __shfl_xor(sq, off);
    half_t* dst = side ? Yf : Xf;
    float*  n2  = side ? n2y : n2x;
    if ((threadIdx.x & 15) == 0)
        n2[q] = side ? sq * LOG2E : sq * (0.25f / LOG2E);
    const int tile16 = q >> 4, c16l = q & 15;
    const int ksi = d4 >> 5, quadi = (d4 >> 3) & 3, j0 = d4 & 7;
    *(f16x4*)&dst[(size_t)tile16 * 1024 + ksi * 512 + (quadi * 16 + c16l) * 8 + j0] = h4;
}

// ---------------------------------------------------------------------------
// K5: RBF via single-term f16 MFMA (consistent-points numerics), frag-major
// loads. Block = 4 waves (2x2), 128x128 tile, 64x64/wave, 32 MFMAs/wave.
// ---------------------------------------------------------------------------
__global__ __launch_bounds__(256, 4) void rbf_kernel(
    const half_t* __restrict__ Xf, const half_t* __restrict__ Yf,
    const float* __restrict__ n2x, const float* __restrict__ n2y,
    float* __restrict__ out)
{
    const int t = threadIdx.x, w = t >> 6, lane = t & 63;
    const int c16 = lane & 15, quad = lane >> 4;
    const int X0 = blockIdx.y * 128 + (w >> 1) * 64;
    const int Y0 = blockIdx.x * 128 + (w & 1) * 64;
    float ny[4];
    f32x4 nx4[4];
#pragma unroll
    for (int yt = 0; yt < 4; ++yt) ny[yt] = n2y[Y0 + 16 * yt + c16];
#pragma unroll
    for (int xt = 0; xt < 4; ++xt)
        nx4[xt] = *(const f32x4*)&n2x[X0 + 16 * xt + 4 * quad];

    const half_t* Xb = Xf + lane * 8;
    const half_t* Yb = Yf + lane * 8;
    f32x4 acc[4][4] = {};   // [xt][yt]
#pragma unroll
    for (int ks = 0; ks < 2; ++ks) {
        f16x8 bh[4];
#pragma unroll
        for (int yt = 0; yt < 4; ++yt)
            bh[yt] = *(const f16x8*)&Yb[(size_t)((Y0 >> 4) + yt) * 1024 + ks * 512];
#pragma unroll
        for (int xt = 0; xt < 4; ++xt) {
            f16x8 ah = *(const f16x8*)&Xb[(size_t)((X0 >> 4) + xt) * 1024 + ks * 512];
#pragma unroll
            for (int yt = 0; yt < 4; ++yt)
                acc[xt][yt] = MFMA32(ah, bh[yt], acc[xt][yt]);
        }
    }
#pragma unroll
    for (int xt = 0; xt < 4; ++xt)
#pragma unroll
        for (int r = 0; r < 4; ++r) {
            int xr = X0 + 16 * xt + 4 * quad + r;
            float nx = nx4[xt][r];
#pragma unroll
            for (int yt = 0; yt < 4; ++yt) {
                float v = exp2f(acc[xt][yt][r] - nx - ny[yt]);
                out[(size_t)xr * N + Y0 + 16 * yt + c16] = v;
            }
        }
}

// ---------------------------------------------------------------------------
extern "C" void kernel_launch(void* const* d_in, const int* in_sizes, int n_in,
                              void* d_out, int out_size, void* d_ws, size_t ws_size,
                              hipStream_t stream) {
    const float* Wq = (const float*)d_in[0];
    const float* Wk = (const float*)d_in[1];
    const float* x  = (const float*)d_in[2];
    const float* y  = (const float*)d_in[3];
    float* out = (float*)d_out;

    char* p = (char*)d_ws;
    size_t used = 0;
    auto alloc = [&](size_t bytes) -> void* {
        void* r = (void*)(p + used);
        used += (bytes + 255) & ~(size_t)255;
        return r;
    };
    half_t* Qfx = (half_t*)alloc((size_t)N * D * 2 * 2);   // hi+lo frag-major
    half_t* Qfy = (half_t*)alloc((size_t)N * D * 2 * 2);
    half_t* Kfx = (half_t*)alloc((size_t)N * D * 2 * 2);
    half_t* Kfy = (half_t*)alloc((size_t)N * D * 2 * 2);
    half_t* Zfx = (half_t*)alloc((size_t)N * D * 2);       // hi only
    half_t* Zfy = (half_t*)alloc((size_t)N * D * 2);
    half_t* Xf  = (half_t*)alloc((size_t)N * D * 2);       // hi only
    half_t* Yf  = (half_t*)alloc((size_t)N * D * 2);
    float*  n2x = (float*) alloc((size_t)N * 4);
    float*  n2y = (float*) alloc((size_t)N * 4);
    half_t* Opart = (half_t*)alloc((size_t)2 * KS * N * D * 2);   // f16 partials
    float*  mpart = (float*) alloc((size_t)2 * KS * N * 4);
    float*  lpart = (float*) alloc((size_t)2 * KS * N * 4);

    proj_kernel<<<dim3(2 * N / 16), 256, 0, stream>>>(Wq, Wk, x, y,
                                                      Qfx, Qfy, Kfx, Kfy);
    ztprep_kernel<<<dim3(N / 32, 2), 256, 0, stream>>>(x, y, Zfx, Zfy);
    attn_kernel<<<dim3(N / 128, 2, KS), 256, 0, stream>>>(
        Qfx, Qfy, Kfx, Kfy, Zfx, Zfy, Opart, mpart, lpart);
    combine_kernel<<<dim3(N / 16, 2), 256, 0, stream>>>(
        Opart, mpart, lpart, Xf, Yf, n2x, n2y);
    rbf_kernel<<<dim3(N / 128, N / 128), 256, 0, stream>>>(Xf, Yf, n2x, n2y, out);
}